// Round 5
// baseline (554.363 us; speedup 1.0000x reference)
//
#include <hip/hip_runtime.h>

typedef unsigned short u16;
typedef __attribute__((ext_vector_type(8))) short short8;
typedef __attribute__((ext_vector_type(4))) float f32x4;

#define GLDS16(gp, sp) __builtin_amdgcn_global_load_lds( \
    (const __attribute__((address_space(1))) void*)(gp),  \
    (__attribute__((address_space(3))) void*)(sp), 16, 0, 0)

__device__ __forceinline__ u16 f2bf(float f) {
  union { float f; unsigned u; } x; x.f = f;
  unsigned r = (x.u + 0x7fffu + ((x.u >> 16) & 1u)) >> 16;  // RNE
  return (u16)r;
}
__device__ __forceinline__ float bf2f(u16 v) {
  union { unsigned u; float f; } x; x.u = ((unsigned)v) << 16; return x.f;
}

// ------- generic weight -> bf16 MFMA B-fragment order --------------------
// W fp32 [2][K][N] -> Wf[l][nb(N/16)][ks(K/32)][lane(64)][e(8)]
//   n = nb*16 + (lane&15); k = ks*32 + (lane>>4)*8 + e
__global__ __launch_bounds__(256) void wswizB(const float* __restrict__ W,
                                              u16* __restrict__ Wf, int K, int N) {
  int tid = blockIdx.x * 256 + threadIdx.x;
  int Kt = K >> 5, Nt = N >> 4;
  int per = Nt * Kt * 64;
  if (tid >= 2 * per) return;
  int l = tid >= per;
  int rem = tid - l * per;
  int nb = rem / (Kt * 64);
  int rem2 = rem - nb * Kt * 64;
  int ks = rem2 >> 6, lane = rem2 & 63;
  int n = nb * 16 + (lane & 15);
  u16 o[8];
  #pragma unroll
  for (int e = 0; e < 8; ++e) {
    int k = ks * 32 + ((lane >> 4) << 3) + e;
    o[e] = f2bf(W[((size_t)l * K + k) * N + n]);
  }
  *(uint4*)(Wf + ((size_t)tid << 3)) = *(uint4*)o;
}

// ------- fc1 weights -> B-fragment order: W1f[l][hc(8)][ks(8)][ntile(8)][lane][8]
__global__ __launch_bounds__(256) void wswiz1(const float* __restrict__ W,
                                              u16* __restrict__ Wf) {
  int tid = blockIdx.x * 256 + threadIdx.x;  // [0, 65536)
  int lane = tid & 63, nt = (tid >> 6) & 7, ks = (tid >> 9) & 7,
      hc = (tid >> 12) & 7, l = tid >> 15;
  int n = hc * 128 + nt * 16 + (lane & 15);
  u16 o[8];
  #pragma unroll
  for (int e = 0; e < 8; ++e) {
    int k = ks * 32 + ((lane >> 4) << 3) + e;
    o[e] = f2bf(W[((size_t)l * 256 + k) * 1024 + n]);
  }
  *(uint4*)(Wf + ((size_t)tid << 3)) = *(uint4*)o;
}

// ------- fc2 weights -> B-fragment order: W2f[l][hc(8)][ks(4)][ntile(16)][lane][8]
__global__ __launch_bounds__(256) void wswiz2(const float* __restrict__ W,
                                              u16* __restrict__ Wf) {
  int tid = blockIdx.x * 256 + threadIdx.x;  // [0, 65536)
  int lane = tid & 63, nt = (tid >> 6) & 15, ks = (tid >> 10) & 3,
      hc = (tid >> 12) & 7, l = tid >> 15;
  int n = nt * 16 + (lane & 15);
  u16 o[8];
  #pragma unroll
  for (int e = 0; e < 8; ++e) {
    int k = hc * 128 + ks * 32 + ((lane >> 4) << 3) + e;
    o[e] = f2bf(W[((size_t)l * 1024 + k) * 256 + n]);
  }
  *(uint4*)(Wf + ((size_t)tid << 3)) = *(uint4*)o;
}

// ------- rel-pos bias gather, bf16, pre-swizzled to MFMA C-layout ------------
__global__ __launch_bounds__(256) void bias_gb(const float* __restrict__ rpb,
                                               const int* __restrict__ rpi,
                                               u16* __restrict__ biasb) {
  int tid = blockIdx.x * 256 + threadIdx.x;  // [0, 2*65536)
  if (tid >= 131072) return;
  int l = tid >> 16, cid = tid & 65535;
  int lane = cid & 63, k = (cid >> 6) & 7, mslot = (cid >> 9) & 15, h = cid >> 13;
  u16 o[8];
  #pragma unroll
  for (int e = 0; e < 8; ++e) {
    int nt = 2 * k + (e >> 2), r = e & 3;
    int i = mslot * 16 + ((lane >> 4) << 2) + r;
    int j = nt * 16 + (lane & 15);
    int idx = rpi[i * 256 + j];
    o[e] = f2bf(rpb[((size_t)l * 961 + idx) * 8 + h]);
  }
  *(uint4*)(biasb + ((size_t)tid << 3)) = *(uint4*)o;
}

// ---------------- LN1 + shift + window partition -> bf16 wins ---------------
__global__ __launch_bounds__(256) void ln_part(const float* __restrict__ x,
                                               const float* __restrict__ g,
                                               const float* __restrict__ b,
                                               u16* __restrict__ out, int shift) {
  int wv = threadIdx.x >> 6, lane = threadIdx.x & 63;
  int wtok = blockIdx.x * 4 + wv;
  int w = wtok >> 8, t = wtok & 255;
  int bimg = w >> 4, wi = w & 15;
  int ph = (((wi >> 2) << 4) + (t >> 4) + shift) & 63;
  int pw = (((wi & 3) << 4) + (t & 15) + shift) & 63;
  const float4 v = *(const float4*)(x + ((size_t)((bimg * 64 + ph) * 64 + pw)) * 256 + lane * 4);
  float s = v.x + v.y + v.z + v.w;
  float sq = v.x * v.x + v.y * v.y + v.z * v.z + v.w * v.w;
  #pragma unroll
  for (int m = 1; m < 64; m <<= 1) { s += __shfl_xor(s, m, 64); sq += __shfl_xor(sq, m, 64); }
  float mean = s * (1.f / 256.f);
  float var = sq * (1.f / 256.f) - mean * mean;
  float rs = rsqrtf(var + 1e-5f);
  float4 gg = *(const float4*)(g + lane * 4);
  float4 bb = *(const float4*)(b + lane * 4);
  u16 o0 = f2bf((v.x - mean) * rs * gg.x + bb.x);
  u16 o1 = f2bf((v.y - mean) * rs * gg.y + bb.y);
  u16 o2 = f2bf((v.z - mean) * rs * gg.z + bb.z);
  u16 o3 = f2bf((v.w - mean) * rs * gg.w + bb.w);
  uint2 pk; pk.x = (unsigned)o0 | ((unsigned)o1 << 16); pk.y = (unsigned)o2 | ((unsigned)o3 << 16);
  *(uint2*)(out + (size_t)wtok * 256 + lane * 4) = pk;
}

// ---------------- GEMM: A[MxK] bf16 row-major, B = pre-swizzled fragments ---
// 128x128 tile, 4 waves (2x2). A staged via global_load_lds; B-fragments read
// straight from L2 (16B/lane coalesced), no B LDS tile.
struct EpiParams {
  const float* bias;
  u16* obf;
  float* of32;
  const float* resid;
  int shift;
  float qscale;
};

// EPI: 0=qkv(bias,q-scale,bf16)  2=proj(bias,window-reverse+unshift+resid -> f32)
template <int EPI>
__global__ __launch_bounds__(256, 4) void gemm_bt(const u16* __restrict__ A,
                                                  const u16* __restrict__ Wf,
                                                  int M, int N, int K, EpiParams ep) {
  __shared__ u16 As[128 * 32];
  int tid = threadIdx.x;
  int n0 = blockIdx.x * 128, m0 = blockIdx.y * 128;
  int wv = tid >> 6, lane = tid & 63, quad = lane >> 4, l15 = lane & 15;
  int wm = wv & 1, wn = wv >> 1;
  int Kt = K >> 5;
  f32x4 acc[4][4] = {};

  for (int k0 = 0; k0 < K; k0 += 32) {
    #pragma unroll
    for (int it = 0; it < 2; ++it) {
      int c = it * 256 + tid;
      int r = c >> 2, kc = (c & 3) * 8;
      GLDS16(A + (size_t)(m0 + r) * K + k0 + kc, &As[c * 8]);
    }
    __syncthreads();
    short8 af[4], bf[4];
    #pragma unroll
    for (int mt = 0; mt < 4; ++mt)
      af[mt] = *(const short8*)&As[(wm * 64 + mt * 16 + l15) * 32 + quad * 8];
    #pragma unroll
    for (int nt = 0; nt < 4; ++nt) {
      size_t ntile = (size_t)(blockIdx.x * 8 + wn * 4 + nt);
      bf[nt] = *(const short8*)(Wf + ((ntile * Kt + (k0 >> 5)) * 64 + lane) * 8);
    }
    #pragma unroll
    for (int mt = 0; mt < 4; ++mt)
      #pragma unroll
      for (int nt = 0; nt < 4; ++nt)
        acc[mt][nt] = __builtin_amdgcn_mfma_f32_16x16x32_bf16(af[mt], bf[nt], acc[mt][nt], 0, 0, 0);
    __syncthreads();
  }

  #pragma unroll
  for (int mt = 0; mt < 4; ++mt) {
    #pragma unroll
    for (int nt = 0; nt < 4; ++nt) {
      #pragma unroll
      for (int r = 0; r < 4; ++r) {
        int grow = m0 + wm * 64 + mt * 16 + quad * 4 + r;
        int gcol = n0 + wn * 64 + nt * 16 + l15;
        float v = acc[mt][nt][r] + ep.bias[gcol];
        if constexpr (EPI == 0) {
          if (gcol < 256) v *= ep.qscale;
          ep.obf[(size_t)grow * N + gcol] = f2bf(v);
        } else {
          int w_ = grow >> 8, t = grow & 255, wi = w_ & 15;
          int ph = (((wi >> 2) << 4) + (t >> 4) + ep.shift) & 63;
          int pw = (((wi & 3) << 4) + (t & 15) + ep.shift) & 63;
          size_t pix = (size_t)(((w_ >> 4) * 64 + ph) * 64 + pw);
          ep.of32[pix * 256 + gcol] = ep.resid[pix * 256 + gcol] + v;
        }
      }
    }
  }
}

// ---------------- fused MLP: LN2 + fc1 + gelu + fc2 + residual --------------
// Block = 64 rows. Weights as pre-swizzled B-fragments from L2. Hidden chunk
// (64x128) in regs -> gelu -> single LDS transpose buffer (2 barriers/chunk).
// LDS = 33792 + 17408 = 51200 B -> 3 blocks/CU.
__global__ __launch_bounds__(256, 3) void fused_mlp(const float* __restrict__ xin,
                                                    const float* __restrict__ g,
                                                    const float* __restrict__ b,
                                                    const u16* __restrict__ W1f,
                                                    const u16* __restrict__ W2f,
                                                    const float* __restrict__ b1p,
                                                    const float* __restrict__ b2p,
                                                    float* __restrict__ out) {
  __shared__ u16 Zs[64 * 264];
  __shared__ u16 Hs[64 * 136];
  int tid = threadIdx.x, wv = tid >> 6, lane = tid & 63;
  int quad = lane >> 4, l15 = lane & 15;
  int m0 = blockIdx.x * 64;

  // LN phase: each wave handles 16 rows
  float4 gg = *(const float4*)(g + lane * 4);
  float4 bb = *(const float4*)(b + lane * 4);
  #pragma unroll 4
  for (int rr = 0; rr < 16; ++rr) {
    int row = wv * 16 + rr;
    const float4 v = *(const float4*)(xin + (size_t)(m0 + row) * 256 + lane * 4);
    float s = v.x + v.y + v.z + v.w;
    float sq = v.x * v.x + v.y * v.y + v.z * v.z + v.w * v.w;
    #pragma unroll
    for (int m = 1; m < 64; m <<= 1) { s += __shfl_xor(s, m, 64); sq += __shfl_xor(sq, m, 64); }
    float mean = s * (1.f / 256.f);
    float var = sq * (1.f / 256.f) - mean * mean;
    float rs = rsqrtf(var + 1e-5f);
    u16 o0 = f2bf((v.x - mean) * rs * gg.x + bb.x);
    u16 o1 = f2bf((v.y - mean) * rs * gg.y + bb.y);
    u16 o2 = f2bf((v.z - mean) * rs * gg.z + bb.z);
    u16 o3 = f2bf((v.w - mean) * rs * gg.w + bb.w);
    uint2 pk; pk.x = (unsigned)o0 | ((unsigned)o1 << 16); pk.y = (unsigned)o2 | ((unsigned)o3 << 16);
    *(uint2*)&Zs[row * 264 + lane * 4] = pk;
  }
  __syncthreads();

  // fc2 accumulators (wave owns cols wv*64..+63)
  f32x4 acc2[4][4];
  #pragma unroll
  for (int nt = 0; nt < 4; ++nt) {
    float b2 = b2p[wv * 64 + nt * 16 + l15];
    #pragma unroll
    for (int mt = 0; mt < 4; ++mt)
      #pragma unroll
      for (int r = 0; r < 4; ++r) acc2[mt][nt][r] = b2;
  }

  for (int hc = 0; hc < 8; ++hc) {
    // ---- phase A: h = z @ W1 chunk (64 x 128; wave owns cols wv*32..+31)
    f32x4 acc1[4][2];
    #pragma unroll
    for (int nt = 0; nt < 2; ++nt) {
      float b1 = b1p[hc * 128 + wv * 32 + nt * 16 + l15];
      #pragma unroll
      for (int mt = 0; mt < 4; ++mt)
        #pragma unroll
        for (int r = 0; r < 4; ++r) acc1[mt][nt][r] = b1;
    }
    #pragma unroll
    for (int ks = 0; ks < 8; ++ks) {
      short8 af[4];
      #pragma unroll
      for (int mt = 0; mt < 4; ++mt)
        af[mt] = *(const short8*)&Zs[(mt * 16 + l15) * 264 + ks * 32 + quad * 8];
      #pragma unroll
      for (int nt = 0; nt < 2; ++nt) {
        short8 bf = *(const short8*)(W1f + ((((size_t)hc * 8 + ks) * 8 + wv * 2 + nt) * 64 + lane) * 8);
        #pragma unroll
        for (int mt = 0; mt < 4; ++mt)
          acc1[mt][nt] = __builtin_amdgcn_mfma_f32_16x16x32_bf16(af[mt], bf, acc1[mt][nt], 0, 0, 0);
      }
    }
    // ---- gelu (sigmoid form, hw rcp) + transpose through LDS
    #pragma unroll
    for (int mt = 0; mt < 4; ++mt)
      #pragma unroll
      for (int nt = 0; nt < 2; ++nt)
        #pragma unroll
        for (int r = 0; r < 4; ++r) {
          float v = acc1[mt][nt][r];
          float inner = v * (1.f + 0.044715f * v * v);
          float e = __expf(-1.5957691216057308f * inner);
          float gl = v * __builtin_amdgcn_rcpf(1.f + e);
          Hs[(mt * 16 + quad * 4 + r) * 136 + wv * 32 + nt * 16 + l15] = f2bf(gl);
        }
    __syncthreads();
    // ---- phase B: out += gelu(h) @ W2 chunk
    #pragma unroll
    for (int ks = 0; ks < 4; ++ks) {
      short8 af2[4];
      #pragma unroll
      for (int mt = 0; mt < 4; ++mt)
        af2[mt] = *(const short8*)&Hs[(mt * 16 + l15) * 136 + ks * 32 + quad * 8];
      #pragma unroll
      for (int nt = 0; nt < 4; ++nt) {
        short8 bf2 = *(const short8*)(W2f + ((((size_t)hc * 4 + ks) * 16 + wv * 4 + nt) * 64 + lane) * 8);
        #pragma unroll
        for (int mt = 0; mt < 4; ++mt)
          acc2[mt][nt] = __builtin_amdgcn_mfma_f32_16x16x32_bf16(af2[mt], bf2, acc2[mt][nt], 0, 0, 0);
      }
    }
    __syncthreads();
  }

  // epilogue: out = xin + acc2
  #pragma unroll
  for (int mt = 0; mt < 4; ++mt)
    #pragma unroll
    for (int nt = 0; nt < 4; ++nt)
      #pragma unroll
      for (int r = 0; r < 4; ++r) {
        size_t idx = (size_t)(m0 + mt * 16 + quad * 4 + r) * 256 + wv * 64 + nt * 16 + l15;
        out[idx] = xin[idx] + acc2[mt][nt][r];
      }
}

// ---------------- fused window attention v3 (round 3, unchanged) ------------
__global__ __launch_bounds__(256, 4) void attn_v3(const u16* __restrict__ qkv,
                                                  const u16* __restrict__ biasb,
                                                  int layer, u16* __restrict__ aout) {
  __shared__ u16 Klds[256 * 32];
  __shared__ u16 Vt[32 * 264];
  __shared__ u16 Plds[4][16 * 40];
  int bid = blockIdx.x;
  int lw = ((bid & 7) << 7) | (bid >> 3);   // XCD swizzle
  int w = lw >> 3, h = lw & 7;
  int tid = threadIdx.x;

  {  // stage K rows + V transposed
    const uint4* kp = (const uint4*)(qkv + ((size_t)(w * 256 + tid)) * 768 + 256 + h * 32);
    uint4* kd = (uint4*)&Klds[tid * 32];
    kd[0] = kp[0]; kd[1] = kp[1]; kd[2] = kp[2]; kd[3] = kp[3];
    const uint4* vp = (const uint4*)(qkv + ((size_t)(w * 256 + tid)) * 768 + 512 + h * 32);
    u16 vt[32];
    *(uint4*)&vt[0]  = vp[0];
    *(uint4*)&vt[8]  = vp[1];
    *(uint4*)&vt[16] = vp[2];
    *(uint4*)&vt[24] = vp[3];
    #pragma unroll
    for (int d = 0; d < 32; ++d) Vt[d * 264 + tid] = vt[d];
  }
  __syncthreads();

  int wv = tid >> 6, lane = tid & 63, quad = lane >> 4, l15 = lane & 15;
  int wi = w & 15, wr = wi >> 2, wc = wi & 3;
  const bool masked = (layer != 0) && (wr == 3 || wc == 3);
  int rcj = (wc == 3) ? (l15 < 8 ? 1 : 2) : 0;

  #pragma unroll
  for (int mt = 0; mt < 4; ++mt) {
    int mslot = wv * 4 + mt;
    int m0 = mslot * 16;
    short8 aq = *(const short8*)(qkv + ((size_t)(w * 256 + m0 + l15)) * 768 + h * 32 + quad * 8);
    const u16* bmt = biasb + ((size_t)layer << 19) + ((size_t)h << 16) + (size_t)mslot * 4096;
    f32x4 c[16];
    #pragma unroll
    for (int k = 0; k < 8; ++k) {
      short8 bv = *(const short8*)(bmt + k * 512 + lane * 8);
      #pragma unroll
      for (int r = 0; r < 4; ++r) {
        c[2 * k][r]     = bf2f((u16)bv[r]);
        c[2 * k + 1][r] = bf2f((u16)bv[4 + r]);
      }
    }
    #pragma unroll
    for (int nt = 0; nt < 16; ++nt) {
      short8 bk = *(const short8*)&Klds[(nt * 16 + l15) * 32 + quad * 8];
      c[nt] = __builtin_amdgcn_mfma_f32_16x16x32_bf16(aq, bk, c[nt], 0, 0, 0);
    }
    if (masked) {
      int regi = ((wr == 3) ? (mslot < 8 ? 1 : 2) : 0) * 3 +
                 ((wc == 3) ? (quad < 2 ? 1 : 2) : 0);
      #pragma unroll
      for (int nt = 0; nt < 16; ++nt) {
        int regj = ((wr == 3) ? (nt < 8 ? 1 : 2) : 0) * 3 + rcj;
        float madd = (regi != regj) ? -100.f : 0.f;
        #pragma unroll
        for (int r = 0; r < 4; ++r) c[nt][r] += madd;
      }
    }
    float pm[4] = {-1e30f, -1e30f, -1e30f, -1e30f};
    #pragma unroll
    for (int nt = 0; nt < 16; ++nt)
      #pragma unroll
      for (int r = 0; r < 4; ++r) pm[r] = fmaxf(pm[r], c[nt][r]);
    #pragma unroll
    for (int r = 0; r < 4; ++r) {
      pm[r] = fmaxf(pm[r], __shfl_xor(pm[r], 1, 64));
      pm[r] = fmaxf(pm[r], __shfl_xor(pm[r], 2, 64));
      pm[r] = fmaxf(pm[r], __shfl_xor(pm[r], 4, 64));
      pm[r] = fmaxf(pm[r], __shfl_xor(pm[r], 8, 64));
    }
    float psum[4] = {0.f, 0.f, 0.f, 0.f};
    #pragma unroll
    for (int nt = 0; nt < 16; ++nt)
      #pragma unroll
      for (int r = 0; r < 4; ++r) {
        float e = __expf(c[nt][r] - pm[r]);
        c[nt][r] = e;
        psum[r] += e;
      }
    #pragma unroll
    for (int r = 0; r < 4; ++r) {
      psum[r] += __shfl_xor(psum[r], 1, 64);
      psum[r] += __shfl_xor(psum[r], 2, 64);
      psum[r] += __shfl_xor(psum[r], 4, 64);
      psum[r] += __shfl_xor(psum[r], 8, 64);
    }
    f32x4 o0 = {0.f, 0.f, 0.f, 0.f}, o1 = {0.f, 0.f, 0.f, 0.f};
    #pragma unroll
    for (int kk = 0; kk < 8; ++kk) {
      #pragma unroll
      for (int r = 0; r < 4; ++r) {
        Plds[wv][(quad * 4 + r) * 40 + l15] = f2bf(c[2 * kk][r]);
        Plds[wv][(quad * 4 + r) * 40 + 16 + l15] = f2bf(c[2 * kk + 1][r]);
      }
      short8 ap = *(const short8*)&Plds[wv][l15 * 40 + quad * 8];
      short8 bv0 = *(const short8*)&Vt[l15 * 264 + kk * 32 + quad * 8];
      short8 bv1 = *(const short8*)&Vt[(16 + l15) * 264 + kk * 32 + quad * 8];
      o0 = __builtin_amdgcn_mfma_f32_16x16x32_bf16(ap, bv0, o0, 0, 0, 0);
      o1 = __builtin_amdgcn_mfma_f32_16x16x32_bf16(ap, bv1, o1, 0, 0, 0);
    }
    #pragma unroll
    for (int r = 0; r < 4; ++r) {
      float inv = 1.f / psum[r];
      size_t row = (size_t)(w * 256 + m0 + quad * 4 + r);
      aout[row * 256 + h * 32 + l15] = f2bf(o0[r] * inv);
      aout[row * 256 + h * 32 + 16 + l15] = f2bf(o1[r] * inv);
    }
  }
}

// ----------------------------------------------------------------------------
extern "C" void kernel_launch(void* const* d_in, const int* in_sizes, int n_in,
                              void* d_out, int out_size, void* d_ws, size_t ws_size,
                              hipStream_t stream) {
  const float* x      = (const float*)d_in[0];
  const float* ln1_g  = (const float*)d_in[1];
  const float* ln1_b  = (const float*)d_in[2];
  const float* qkv_w  = (const float*)d_in[3];
  const float* qkv_b  = (const float*)d_in[4];
  const float* rpb    = (const float*)d_in[5];
  const float* proj_w = (const float*)d_in[6];
  const float* proj_b = (const float*)d_in[7];
  const float* ln2_g  = (const float*)d_in[8];
  const float* ln2_b  = (const float*)d_in[9];
  const float* fc1_w  = (const float*)d_in[10];
  const float* fc1_b  = (const float*)d_in[11];
  const float* fc2_w  = (const float*)d_in[12];
  const float* fc2_b  = (const float*)d_in[13];
  const int*   rpi    = (const int*)d_in[15];

  char* ws = (char*)d_ws;
  size_t off = 0;
  auto alloc = [&](size_t bytes) { void* p = ws + off; off += (bytes + 255) & ~(size_t)255; return p; };
  float* x_cur   = (float*)alloc((size_t)32768 * 256 * 4);   // residual stream
  u16* sbuf      = (u16*)alloc((size_t)32768 * 256 * 2);     // wins -> attn_out
  u16* qkvb      = (u16*)alloc((size_t)32768 * 768 * 2);
  u16* biasb     = (u16*)alloc((size_t)2 * 8 * 65536 * 2);   // pre-swizzled bf16 bias
  u16* qkvF      = (u16*)alloc((size_t)2 * 196608 * 2);      // qkv B-fragments
  u16* projF     = (u16*)alloc((size_t)2 * 65536 * 2);       // proj B-fragments
  u16* W1f       = (u16*)alloc((size_t)2 * 262144 * 2);      // fc1 B-fragments
  u16* W2f       = (u16*)alloc((size_t)2 * 262144 * 2);      // fc2 B-fragments

  // prep
  wswizB<<<192, 256, 0, stream>>>(qkv_w, qkvF, 256, 768);
  wswizB<<<64, 256, 0, stream>>>(proj_w, projF, 256, 256);
  wswiz1<<<256, 256, 0, stream>>>(fc1_w, W1f);
  wswiz2<<<256, 256, 0, stream>>>(fc2_w, W2f);
  bias_gb<<<512, 256, 0, stream>>>(rpb, rpi, biasb);

  for (int i = 0; i < 2; ++i) {
    int shift = i ? 8 : 0;
    const float* xin = i ? x_cur : x;

    ln_part<<<8192, 256, 0, stream>>>(xin, ln1_g + i * 256, ln1_b + i * 256, sbuf, shift);

    EpiParams ep{};
    ep.bias = qkv_b + i * 768; ep.obf = qkvb; ep.qscale = 0.17677669529663687f;
    gemm_bt<0><<<dim3(6, 256), 256, 0, stream>>>(sbuf, qkvF + (size_t)i * 196608, 32768, 768, 256, ep);

    attn_v3<<<1024, 256, 0, stream>>>(qkvb, biasb, i, sbuf);

    ep = EpiParams{};
    ep.bias = proj_b + i * 256; ep.of32 = x_cur; ep.resid = xin; ep.shift = shift;
    gemm_bt<2><<<dim3(2, 256), 256, 0, stream>>>(sbuf, projF + (size_t)i * 65536, 32768, 256, 256, ep);

    fused_mlp<<<512, 256, 0, stream>>>(x_cur, ln2_g + i * 256, ln2_b + i * 256,
                                       W1f + (size_t)i * 262144, W2f + (size_t)i * 262144,
                                       fc1_b + i * 1024, fc2_b + i * 256,
                                       (i == 1) ? (float*)d_out : x_cur);
  }
}

// Round 6
// 424.631 us; speedup vs baseline: 1.3055x; 1.3055x over previous
//
#include <hip/hip_runtime.h>

typedef unsigned short u16;
typedef __attribute__((ext_vector_type(8))) short short8;
typedef __attribute__((ext_vector_type(4))) float f32x4;

#define GLDS16(gp, sp) __builtin_amdgcn_global_load_lds( \
    (const __attribute__((address_space(1))) void*)(gp),  \
    (__attribute__((address_space(3))) void*)(sp), 16, 0, 0)

__device__ __forceinline__ u16 f2bf(float f) {
  union { float f; unsigned u; } x; x.f = f;
  unsigned r = (x.u + 0x7fffu + ((x.u >> 16) & 1u)) >> 16;  // RNE
  return (u16)r;
}
__device__ __forceinline__ float bf2f(u16 v) {
  union { unsigned u; float f; } x; x.u = ((unsigned)v) << 16; return x.f;
}

// ------- generic weight -> bf16 MFMA B-fragment order --------------------
// W fp32 [2][K][N] -> Wf[l][nb(N/16)][ks(K/32)][lane(64)][e(8)]
//   n = nb*16 + (lane&15); k = ks*32 + (lane>>4)*8 + e
__global__ __launch_bounds__(256) void wswizB(const float* __restrict__ W,
                                              u16* __restrict__ Wf, int K, int N) {
  int tid = blockIdx.x * 256 + threadIdx.x;
  int Kt = K >> 5, Nt = N >> 4;
  int per = Nt * Kt * 64;
  if (tid >= 2 * per) return;
  int l = tid >= per;
  int rem = tid - l * per;
  int nb = rem / (Kt * 64);
  int rem2 = rem - nb * Kt * 64;
  int ks = rem2 >> 6, lane = rem2 & 63;
  int n = nb * 16 + (lane & 15);
  u16 o[8];
  #pragma unroll
  for (int e = 0; e < 8; ++e) {
    int k = ks * 32 + ((lane >> 4) << 3) + e;
    o[e] = f2bf(W[((size_t)l * K + k) * N + n]);
  }
  *(uint4*)(Wf + ((size_t)tid << 3)) = *(uint4*)o;
}

// ------- fc1 weights -> B-fragment order: W1f[l][hc(8)][ks(8)][ntile(8)][lane][8]
__global__ __launch_bounds__(256) void wswiz1(const float* __restrict__ W,
                                              u16* __restrict__ Wf) {
  int tid = blockIdx.x * 256 + threadIdx.x;  // [0, 65536)
  int lane = tid & 63, nt = (tid >> 6) & 7, ks = (tid >> 9) & 7,
      hc = (tid >> 12) & 7, l = tid >> 15;
  int n = hc * 128 + nt * 16 + (lane & 15);
  u16 o[8];
  #pragma unroll
  for (int e = 0; e < 8; ++e) {
    int k = ks * 32 + ((lane >> 4) << 3) + e;
    o[e] = f2bf(W[((size_t)l * 256 + k) * 1024 + n]);
  }
  *(uint4*)(Wf + ((size_t)tid << 3)) = *(uint4*)o;
}

// ------- fc2 weights -> B-fragment order: W2f[l][hc(8)][ks(4)][ntile(16)][lane][8]
__global__ __launch_bounds__(256) void wswiz2(const float* __restrict__ W,
                                              u16* __restrict__ Wf) {
  int tid = blockIdx.x * 256 + threadIdx.x;  // [0, 65536)
  int lane = tid & 63, nt = (tid >> 6) & 15, ks = (tid >> 10) & 3,
      hc = (tid >> 12) & 7, l = tid >> 15;
  int n = nt * 16 + (lane & 15);
  u16 o[8];
  #pragma unroll
  for (int e = 0; e < 8; ++e) {
    int k = hc * 128 + ks * 32 + ((lane >> 4) << 3) + e;
    o[e] = f2bf(W[((size_t)l * 1024 + k) * 256 + n]);
  }
  *(uint4*)(Wf + ((size_t)tid << 3)) = *(uint4*)o;
}

// ------- rel-pos bias gather, bf16, pre-swizzled to MFMA C-layout ------------
__global__ __launch_bounds__(256) void bias_gb(const float* __restrict__ rpb,
                                               const int* __restrict__ rpi,
                                               u16* __restrict__ biasb) {
  int tid = blockIdx.x * 256 + threadIdx.x;  // [0, 2*65536)
  if (tid >= 131072) return;
  int l = tid >> 16, cid = tid & 65535;
  int lane = cid & 63, k = (cid >> 6) & 7, mslot = (cid >> 9) & 15, h = cid >> 13;
  u16 o[8];
  #pragma unroll
  for (int e = 0; e < 8; ++e) {
    int nt = 2 * k + (e >> 2), r = e & 3;
    int i = mslot * 16 + ((lane >> 4) << 2) + r;
    int j = nt * 16 + (lane & 15);
    int idx = rpi[i * 256 + j];
    o[e] = f2bf(rpb[((size_t)l * 961 + idx) * 8 + h]);
  }
  *(uint4*)(biasb + ((size_t)tid << 3)) = *(uint4*)o;
}

// ---------------- LN1 + shift + window partition -> bf16 wins ---------------
__global__ __launch_bounds__(256) void ln_part(const float* __restrict__ x,
                                               const float* __restrict__ g,
                                               const float* __restrict__ b,
                                               u16* __restrict__ out, int shift) {
  int wv = threadIdx.x >> 6, lane = threadIdx.x & 63;
  int wtok = blockIdx.x * 4 + wv;
  int w = wtok >> 8, t = wtok & 255;
  int bimg = w >> 4, wi = w & 15;
  int ph = (((wi >> 2) << 4) + (t >> 4) + shift) & 63;
  int pw = (((wi & 3) << 4) + (t & 15) + shift) & 63;
  const float4 v = *(const float4*)(x + ((size_t)((bimg * 64 + ph) * 64 + pw)) * 256 + lane * 4);
  float s = v.x + v.y + v.z + v.w;
  float sq = v.x * v.x + v.y * v.y + v.z * v.z + v.w * v.w;
  #pragma unroll
  for (int m = 1; m < 64; m <<= 1) { s += __shfl_xor(s, m, 64); sq += __shfl_xor(sq, m, 64); }
  float mean = s * (1.f / 256.f);
  float var = sq * (1.f / 256.f) - mean * mean;
  float rs = rsqrtf(var + 1e-5f);
  float4 gg = *(const float4*)(g + lane * 4);
  float4 bb = *(const float4*)(b + lane * 4);
  u16 o0 = f2bf((v.x - mean) * rs * gg.x + bb.x);
  u16 o1 = f2bf((v.y - mean) * rs * gg.y + bb.y);
  u16 o2 = f2bf((v.z - mean) * rs * gg.z + bb.z);
  u16 o3 = f2bf((v.w - mean) * rs * gg.w + bb.w);
  uint2 pk; pk.x = (unsigned)o0 | ((unsigned)o1 << 16); pk.y = (unsigned)o2 | ((unsigned)o3 << 16);
  *(uint2*)(out + (size_t)wtok * 256 + lane * 4) = pk;
}

// ---------------- GEMM: A[MxK] bf16 row-major, B = pre-swizzled fragments ---
struct EpiParams {
  const float* bias;
  u16* obf;
  float* of32;
  const float* resid;
  int shift;
  float qscale;
};

// EPI: 0=qkv(bias,q-scale,bf16)  2=proj(bias,window-reverse+unshift+resid -> f32)
template <int EPI>
__global__ __launch_bounds__(256, 4) void gemm_bt(const u16* __restrict__ A,
                                                  const u16* __restrict__ Wf,
                                                  int M, int N, int K, EpiParams ep) {
  __shared__ u16 As[128 * 32];
  int tid = threadIdx.x;
  int n0 = blockIdx.x * 128, m0 = blockIdx.y * 128;
  int wv = tid >> 6, lane = tid & 63, quad = lane >> 4, l15 = lane & 15;
  int wm = wv & 1, wn = wv >> 1;
  int Kt = K >> 5;
  f32x4 acc[4][4] = {};

  for (int k0 = 0; k0 < K; k0 += 32) {
    #pragma unroll
    for (int it = 0; it < 2; ++it) {
      int c = it * 256 + tid;
      int r = c >> 2, kc = (c & 3) * 8;
      GLDS16(A + (size_t)(m0 + r) * K + k0 + kc, &As[c * 8]);
    }
    __syncthreads();
    short8 af[4], bf[4];
    #pragma unroll
    for (int mt = 0; mt < 4; ++mt)
      af[mt] = *(const short8*)&As[(wm * 64 + mt * 16 + l15) * 32 + quad * 8];
    #pragma unroll
    for (int nt = 0; nt < 4; ++nt) {
      size_t ntile = (size_t)(blockIdx.x * 8 + wn * 4 + nt);
      bf[nt] = *(const short8*)(Wf + ((ntile * Kt + (k0 >> 5)) * 64 + lane) * 8);
    }
    #pragma unroll
    for (int mt = 0; mt < 4; ++mt)
      #pragma unroll
      for (int nt = 0; nt < 4; ++nt)
        acc[mt][nt] = __builtin_amdgcn_mfma_f32_16x16x32_bf16(af[mt], bf[nt], acc[mt][nt], 0, 0, 0);
    __syncthreads();
  }

  #pragma unroll
  for (int mt = 0; mt < 4; ++mt) {
    #pragma unroll
    for (int nt = 0; nt < 4; ++nt) {
      #pragma unroll
      for (int r = 0; r < 4; ++r) {
        int grow = m0 + wm * 64 + mt * 16 + quad * 4 + r;
        int gcol = n0 + wn * 64 + nt * 16 + l15;
        float v = acc[mt][nt][r] + ep.bias[gcol];
        if constexpr (EPI == 0) {
          if (gcol < 256) v *= ep.qscale;
          ep.obf[(size_t)grow * N + gcol] = f2bf(v);
        } else {
          int w_ = grow >> 8, t = grow & 255, wi = w_ & 15;
          int ph = (((wi >> 2) << 4) + (t >> 4) + ep.shift) & 63;
          int pw = (((wi & 3) << 4) + (t & 15) + ep.shift) & 63;
          size_t pix = (size_t)(((w_ >> 4) * 64 + ph) * 64 + pw);
          ep.of32[pix * 256 + gcol] = ep.resid[pix * 256 + gcol] + v;
        }
      }
    }
  }
}

// ---------------- fused MLP v3: 512 threads (8 waves), 64-row tile ----------
// 2 blocks/CU x 8 waves = 16 waves/CU. Double-buffered Hs, 1 barrier/chunk.
// Phase A: wave owns 16 hidden cols (acc1[4][1]); Phase B: 32 out cols
// (acc2[4][2]). Weights as pre-swizzled B-fragments from L2.
// LDS = 33792 (Zs) + 2*17408 (Hs) = 68608 B.
__global__ __launch_bounds__(512, 4) void fused_mlp(const float* __restrict__ xin,
                                                    const float* __restrict__ g,
                                                    const float* __restrict__ b,
                                                    const u16* __restrict__ W1f,
                                                    const u16* __restrict__ W2f,
                                                    const float* __restrict__ b1p,
                                                    const float* __restrict__ b2p,
                                                    float* __restrict__ out) {
  __shared__ u16 Zs[64 * 264];
  __shared__ u16 Hs[2][64 * 136];
  int tid = threadIdx.x, wv = tid >> 6, lane = tid & 63;
  int quad = lane >> 4, l15 = lane & 15;
  int m0 = blockIdx.x * 64;

  // LN phase: each wave handles 8 rows
  float4 gg = *(const float4*)(g + lane * 4);
  float4 bb = *(const float4*)(b + lane * 4);
  #pragma unroll
  for (int rr = 0; rr < 8; ++rr) {
    int row = wv * 8 + rr;
    const float4 v = *(const float4*)(xin + (size_t)(m0 + row) * 256 + lane * 4);
    float s = v.x + v.y + v.z + v.w;
    float sq = v.x * v.x + v.y * v.y + v.z * v.z + v.w * v.w;
    #pragma unroll
    for (int m = 1; m < 64; m <<= 1) { s += __shfl_xor(s, m, 64); sq += __shfl_xor(sq, m, 64); }
    float mean = s * (1.f / 256.f);
    float var = sq * (1.f / 256.f) - mean * mean;
    float rs = rsqrtf(var + 1e-5f);
    u16 o0 = f2bf((v.x - mean) * rs * gg.x + bb.x);
    u16 o1 = f2bf((v.y - mean) * rs * gg.y + bb.y);
    u16 o2 = f2bf((v.z - mean) * rs * gg.z + bb.z);
    u16 o3 = f2bf((v.w - mean) * rs * gg.w + bb.w);
    uint2 pk; pk.x = (unsigned)o0 | ((unsigned)o1 << 16); pk.y = (unsigned)o2 | ((unsigned)o3 << 16);
    *(uint2*)&Zs[row * 264 + lane * 4] = pk;
  }
  __syncthreads();

  // fc2 accumulators: wave owns out cols wv*32 .. +31
  f32x4 acc2[4][2];
  #pragma unroll
  for (int nt = 0; nt < 2; ++nt) {
    float b2 = b2p[wv * 32 + nt * 16 + l15];
    #pragma unroll
    for (int mt = 0; mt < 4; ++mt)
      #pragma unroll
      for (int r = 0; r < 4; ++r) acc2[mt][nt][r] = b2;
  }

  for (int hc = 0; hc < 8; ++hc) {
    // ---- phase A: h = z @ W1 chunk (64 x 128; wave owns cols hc*128+wv*16..+15)
    f32x4 acc1[4];
    {
      float b1 = b1p[hc * 128 + wv * 16 + l15];
      #pragma unroll
      for (int mt = 0; mt < 4; ++mt)
        #pragma unroll
        for (int r = 0; r < 4; ++r) acc1[mt][r] = b1;
    }
    #pragma unroll
    for (int ks = 0; ks < 8; ++ks) {
      short8 bf = *(const short8*)(W1f + ((((size_t)hc * 8 + ks) * 8 + wv) * 64 + lane) * 8);
      #pragma unroll
      for (int mt = 0; mt < 4; ++mt) {
        short8 af = *(const short8*)&Zs[(mt * 16 + l15) * 264 + ks * 32 + quad * 8];
        acc1[mt] = __builtin_amdgcn_mfma_f32_16x16x32_bf16(af, bf, acc1[mt], 0, 0, 0);
      }
    }
    // ---- gelu (sigmoid form, hw rcp) + transpose into double-buffered LDS
    u16* hs = &Hs[hc & 1][0];
    #pragma unroll
    for (int mt = 0; mt < 4; ++mt)
      #pragma unroll
      for (int r = 0; r < 4; ++r) {
        float v = acc1[mt][r];
        float inner = v * (1.f + 0.044715f * v * v);
        float e = __expf(-1.5957691216057308f * inner);
        float gl = v * __builtin_amdgcn_rcpf(1.f + e);
        hs[(mt * 16 + quad * 4 + r) * 136 + wv * 16 + l15] = f2bf(gl);
      }
    __syncthreads();
    // ---- phase B: out += gelu(h) @ W2 chunk
    #pragma unroll
    for (int ks = 0; ks < 4; ++ks) {
      short8 bf2[2];
      #pragma unroll
      for (int nt = 0; nt < 2; ++nt)
        bf2[nt] = *(const short8*)(W2f + ((((size_t)hc * 4 + ks) * 16 + wv * 2 + nt) * 64 + lane) * 8);
      #pragma unroll
      for (int mt = 0; mt < 4; ++mt) {
        short8 af2 = *(const short8*)&hs[(mt * 16 + l15) * 136 + ks * 32 + quad * 8];
        #pragma unroll
        for (int nt = 0; nt < 2; ++nt)
          acc2[mt][nt] = __builtin_amdgcn_mfma_f32_16x16x32_bf16(af2, bf2[nt], acc2[mt][nt], 0, 0, 0);
      }
    }
  }

  // epilogue: out = xin + acc2
  #pragma unroll
  for (int mt = 0; mt < 4; ++mt)
    #pragma unroll
    for (int nt = 0; nt < 2; ++nt)
      #pragma unroll
      for (int r = 0; r < 4; ++r) {
        size_t idx = (size_t)(m0 + mt * 16 + quad * 4 + r) * 256 + wv * 32 + nt * 16 + l15;
        out[idx] = xin[idx] + acc2[mt][nt][r];
      }
}

// ---------------- fused window attention v3 (round 3, unchanged) ------------
__global__ __launch_bounds__(256, 4) void attn_v3(const u16* __restrict__ qkv,
                                                  const u16* __restrict__ biasb,
                                                  int layer, u16* __restrict__ aout) {
  __shared__ u16 Klds[256 * 32];
  __shared__ u16 Vt[32 * 264];
  __shared__ u16 Plds[4][16 * 40];
  int bid = blockIdx.x;
  int lw = ((bid & 7) << 7) | (bid >> 3);   // XCD swizzle
  int w = lw >> 3, h = lw & 7;
  int tid = threadIdx.x;

  {  // stage K rows + V transposed
    const uint4* kp = (const uint4*)(qkv + ((size_t)(w * 256 + tid)) * 768 + 256 + h * 32);
    uint4* kd = (uint4*)&Klds[tid * 32];
    kd[0] = kp[0]; kd[1] = kp[1]; kd[2] = kp[2]; kd[3] = kp[3];
    const uint4* vp = (const uint4*)(qkv + ((size_t)(w * 256 + tid)) * 768 + 512 + h * 32);
    u16 vt[32];
    *(uint4*)&vt[0]  = vp[0];
    *(uint4*)&vt[8]  = vp[1];
    *(uint4*)&vt[16] = vp[2];
    *(uint4*)&vt[24] = vp[3];
    #pragma unroll
    for (int d = 0; d < 32; ++d) Vt[d * 264 + tid] = vt[d];
  }
  __syncthreads();

  int wv = tid >> 6, lane = tid & 63, quad = lane >> 4, l15 = lane & 15;
  int wi = w & 15, wr = wi >> 2, wc = wi & 3;
  const bool masked = (layer != 0) && (wr == 3 || wc == 3);
  int rcj = (wc == 3) ? (l15 < 8 ? 1 : 2) : 0;

  #pragma unroll
  for (int mt = 0; mt < 4; ++mt) {
    int mslot = wv * 4 + mt;
    int m0 = mslot * 16;
    short8 aq = *(const short8*)(qkv + ((size_t)(w * 256 + m0 + l15)) * 768 + h * 32 + quad * 8);
    const u16* bmt = biasb + ((size_t)layer << 19) + ((size_t)h << 16) + (size_t)mslot * 4096;
    f32x4 c[16];
    #pragma unroll
    for (int k = 0; k < 8; ++k) {
      short8 bv = *(const short8*)(bmt + k * 512 + lane * 8);
      #pragma unroll
      for (int r = 0; r < 4; ++r) {
        c[2 * k][r]     = bf2f((u16)bv[r]);
        c[2 * k + 1][r] = bf2f((u16)bv[4 + r]);
      }
    }
    #pragma unroll
    for (int nt = 0; nt < 16; ++nt) {
      short8 bk = *(const short8*)&Klds[(nt * 16 + l15) * 32 + quad * 8];
      c[nt] = __builtin_amdgcn_mfma_f32_16x16x32_bf16(aq, bk, c[nt], 0, 0, 0);
    }
    if (masked) {
      int regi = ((wr == 3) ? (mslot < 8 ? 1 : 2) : 0) * 3 +
                 ((wc == 3) ? (quad < 2 ? 1 : 2) : 0);
      #pragma unroll
      for (int nt = 0; nt < 16; ++nt) {
        int regj = ((wr == 3) ? (nt < 8 ? 1 : 2) : 0) * 3 + rcj;
        float madd = (regi != regj) ? -100.f : 0.f;
        #pragma unroll
        for (int r = 0; r < 4; ++r) c[nt][r] += madd;
      }
    }
    float pm[4] = {-1e30f, -1e30f, -1e30f, -1e30f};
    #pragma unroll
    for (int nt = 0; nt < 16; ++nt)
      #pragma unroll
      for (int r = 0; r < 4; ++r) pm[r] = fmaxf(pm[r], c[nt][r]);
    #pragma unroll
    for (int r = 0; r < 4; ++r) {
      pm[r] = fmaxf(pm[r], __shfl_xor(pm[r], 1, 64));
      pm[r] = fmaxf(pm[r], __shfl_xor(pm[r], 2, 64));
      pm[r] = fmaxf(pm[r], __shfl_xor(pm[r], 4, 64));
      pm[r] = fmaxf(pm[r], __shfl_xor(pm[r], 8, 64));
    }
    float psum[4] = {0.f, 0.f, 0.f, 0.f};
    #pragma unroll
    for (int nt = 0; nt < 16; ++nt)
      #pragma unroll
      for (int r = 0; r < 4; ++r) {
        float e = __expf(c[nt][r] - pm[r]);
        c[nt][r] = e;
        psum[r] += e;
      }
    #pragma unroll
    for (int r = 0; r < 4; ++r) {
      psum[r] += __shfl_xor(psum[r], 1, 64);
      psum[r] += __shfl_xor(psum[r], 2, 64);
      psum[r] += __shfl_xor(psum[r], 4, 64);
      psum[r] += __shfl_xor(psum[r], 8, 64);
    }
    f32x4 o0 = {0.f, 0.f, 0.f, 0.f}, o1 = {0.f, 0.f, 0.f, 0.f};
    #pragma unroll
    for (int kk = 0; kk < 8; ++kk) {
      #pragma unroll
      for (int r = 0; r < 4; ++r) {
        Plds[wv][(quad * 4 + r) * 40 + l15] = f2bf(c[2 * kk][r]);
        Plds[wv][(quad * 4 + r) * 40 + 16 + l15] = f2bf(c[2 * kk + 1][r]);
      }
      short8 ap = *(const short8*)&Plds[wv][l15 * 40 + quad * 8];
      short8 bv0 = *(const short8*)&Vt[l15 * 264 + kk * 32 + quad * 8];
      short8 bv1 = *(const short8*)&Vt[(16 + l15) * 264 + kk * 32 + quad * 8];
      o0 = __builtin_amdgcn_mfma_f32_16x16x32_bf16(ap, bv0, o0, 0, 0, 0);
      o1 = __builtin_amdgcn_mfma_f32_16x16x32_bf16(ap, bv1, o1, 0, 0, 0);
    }
    #pragma unroll
    for (int r = 0; r < 4; ++r) {
      float inv = 1.f / psum[r];
      size_t row = (size_t)(w * 256 + m0 + quad * 4 + r);
      aout[row * 256 + h * 32 + l15] = f2bf(o0[r] * inv);
      aout[row * 256 + h * 32 + 16 + l15] = f2bf(o1[r] * inv);
    }
  }
}

// ----------------------------------------------------------------------------
extern "C" void kernel_launch(void* const* d_in, const int* in_sizes, int n_in,
                              void* d_out, int out_size, void* d_ws, size_t ws_size,
                              hipStream_t stream) {
  const float* x      = (const float*)d_in[0];
  const float* ln1_g  = (const float*)d_in[1];
  const float* ln1_b  = (const float*)d_in[2];
  const float* qkv_w  = (const float*)d_in[3];
  const float* qkv_b  = (const float*)d_in[4];
  const float* rpb    = (const float*)d_in[5];
  const float* proj_w = (const float*)d_in[6];
  const float* proj_b = (const float*)d_in[7];
  const float* ln2_g  = (const float*)d_in[8];
  const float* ln2_b  = (const float*)d_in[9];
  const float* fc1_w  = (const float*)d_in[10];
  const float* fc1_b  = (const float*)d_in[11];
  const float* fc2_w  = (const float*)d_in[12];
  const float* fc2_b  = (const float*)d_in[13];
  const int*   rpi    = (const int*)d_in[15];

  char* ws = (char*)d_ws;
  size_t off = 0;
  auto alloc = [&](size_t bytes) { void* p = ws + off; off += (bytes + 255) & ~(size_t)255; return p; };
  float* x_cur   = (float*)alloc((size_t)32768 * 256 * 4);   // residual stream
  u16* sbuf      = (u16*)alloc((size_t)32768 * 256 * 2);     // wins -> attn_out
  u16* qkvb      = (u16*)alloc((size_t)32768 * 768 * 2);
  u16* biasb     = (u16*)alloc((size_t)2 * 8 * 65536 * 2);   // pre-swizzled bf16 bias
  u16* qkvF      = (u16*)alloc((size_t)2 * 196608 * 2);      // qkv B-fragments
  u16* projF     = (u16*)alloc((size_t)2 * 65536 * 2);       // proj B-fragments
  u16* W1f       = (u16*)alloc((size_t)2 * 262144 * 2);      // fc1 B-fragments
  u16* W2f       = (u16*)alloc((size_t)2 * 262144 * 2);      // fc2 B-fragments

  // prep
  wswizB<<<192, 256, 0, stream>>>(qkv_w, qkvF, 256, 768);
  wswizB<<<64, 256, 0, stream>>>(proj_w, projF, 256, 256);
  wswiz1<<<256, 256, 0, stream>>>(fc1_w, W1f);
  wswiz2<<<256, 256, 0, stream>>>(fc2_w, W2f);
  bias_gb<<<512, 256, 0, stream>>>(rpb, rpi, biasb);

  for (int i = 0; i < 2; ++i) {
    int shift = i ? 8 : 0;
    const float* xin = i ? x_cur : x;

    ln_part<<<8192, 256, 0, stream>>>(xin, ln1_g + i * 256, ln1_b + i * 256, sbuf, shift);

    EpiParams ep{};
    ep.bias = qkv_b + i * 768; ep.obf = qkvb; ep.qscale = 0.17677669529663687f;
    gemm_bt<0><<<dim3(6, 256), 256, 0, stream>>>(sbuf, qkvF + (size_t)i * 196608, 32768, 768, 256, ep);

    attn_v3<<<1024, 256, 0, stream>>>(qkvb, biasb, i, sbuf);

    ep = EpiParams{};
    ep.bias = proj_b + i * 256; ep.of32 = x_cur; ep.resid = xin; ep.shift = shift;
    gemm_bt<2><<<dim3(2, 256), 256, 0, stream>>>(sbuf, projF + (size_t)i * 65536, 32768, 256, 256, ep);

    fused_mlp<<<512, 512, 0, stream>>>(x_cur, ln2_g + i * 256, ln2_b + i * 256,
                                       W1f + (size_t)i * 262144, W2f + (size_t)i * 262144,
                                       fc1_b + i * 1024, fc2_b + i * 256,
                                       (i == 1) ? (float*)d_out : x_cur);
  }
}

// Round 7
// 423.603 us; speedup vs baseline: 1.3087x; 1.0024x over previous
//
#include <hip/hip_runtime.h>

typedef unsigned short u16;
typedef __attribute__((ext_vector_type(8))) short short8;
typedef __attribute__((ext_vector_type(4))) float f32x4;

#define GLDS16(gp, sp) __builtin_amdgcn_global_load_lds( \
    (const __attribute__((address_space(1))) void*)(gp),  \
    (__attribute__((address_space(3))) void*)(sp), 16, 0, 0)

__device__ __forceinline__ u16 f2bf(float f) {
  union { float f; unsigned u; } x; x.f = f;
  unsigned r = (x.u + 0x7fffu + ((x.u >> 16) & 1u)) >> 16;  // RNE
  return (u16)r;
}
__device__ __forceinline__ float bf2f(u16 v) {
  union { unsigned u; float f; } x; x.u = ((unsigned)v) << 16; return x.f;
}

// ------- generic weight -> bf16 MFMA B-fragment order --------------------
// W fp32 [2][K][N] -> Wf[l][nb(N/16)][ks(K/32)][lane(64)][e(8)]
//   n = nb*16 + (lane&15); k = ks*32 + (lane>>4)*8 + e
__global__ __launch_bounds__(256) void wswizB(const float* __restrict__ W,
                                              u16* __restrict__ Wf, int K, int N) {
  int tid = blockIdx.x * 256 + threadIdx.x;
  int Kt = K >> 5, Nt = N >> 4;
  int per = Nt * Kt * 64;
  if (tid >= 2 * per) return;
  int l = tid >= per;
  int rem = tid - l * per;
  int nb = rem / (Kt * 64);
  int rem2 = rem - nb * Kt * 64;
  int ks = rem2 >> 6, lane = rem2 & 63;
  int n = nb * 16 + (lane & 15);
  u16 o[8];
  #pragma unroll
  for (int e = 0; e < 8; ++e) {
    int k = ks * 32 + ((lane >> 4) << 3) + e;
    o[e] = f2bf(W[((size_t)l * K + k) * N + n]);
  }
  *(uint4*)(Wf + ((size_t)tid << 3)) = *(uint4*)o;
}

// ------- fc1 weights -> B-fragment order: W1f[l][hc(8)][ks(8)][ntile(8)][lane][8]
__global__ __launch_bounds__(256) void wswiz1(const float* __restrict__ W,
                                              u16* __restrict__ Wf) {
  int tid = blockIdx.x * 256 + threadIdx.x;  // [0, 65536)
  int lane = tid & 63, nt = (tid >> 6) & 7, ks = (tid >> 9) & 7,
      hc = (tid >> 12) & 7, l = tid >> 15;
  int n = hc * 128 + nt * 16 + (lane & 15);
  u16 o[8];
  #pragma unroll
  for (int e = 0; e < 8; ++e) {
    int k = ks * 32 + ((lane >> 4) << 3) + e;
    o[e] = f2bf(W[((size_t)l * 256 + k) * 1024 + n]);
  }
  *(uint4*)(Wf + ((size_t)tid << 3)) = *(uint4*)o;
}

// ------- fc2 weights -> B-fragment order: W2f[l][hc(8)][ks(4)][ntile(16)][lane][8]
__global__ __launch_bounds__(256) void wswiz2(const float* __restrict__ W,
                                              u16* __restrict__ Wf) {
  int tid = blockIdx.x * 256 + threadIdx.x;  // [0, 65536)
  int lane = tid & 63, nt = (tid >> 6) & 15, ks = (tid >> 10) & 3,
      hc = (tid >> 12) & 7, l = tid >> 15;
  int n = nt * 16 + (lane & 15);
  u16 o[8];
  #pragma unroll
  for (int e = 0; e < 8; ++e) {
    int k = hc * 128 + ks * 32 + ((lane >> 4) << 3) + e;
    o[e] = f2bf(W[((size_t)l * 1024 + k) * 256 + n]);
  }
  *(uint4*)(Wf + ((size_t)tid << 3)) = *(uint4*)o;
}

// ------- rel-pos bias gather, bf16, pre-swizzled to MFMA C-layout ------------
__global__ __launch_bounds__(256) void bias_gb(const float* __restrict__ rpb,
                                               const int* __restrict__ rpi,
                                               u16* __restrict__ biasb) {
  int tid = blockIdx.x * 256 + threadIdx.x;  // [0, 2*65536)
  if (tid >= 131072) return;
  int l = tid >> 16, cid = tid & 65535;
  int lane = cid & 63, k = (cid >> 6) & 7, mslot = (cid >> 9) & 15, h = cid >> 13;
  u16 o[8];
  #pragma unroll
  for (int e = 0; e < 8; ++e) {
    int nt = 2 * k + (e >> 2), r = e & 3;
    int i = mslot * 16 + ((lane >> 4) << 2) + r;
    int j = nt * 16 + (lane & 15);
    int idx = rpi[i * 256 + j];
    o[e] = f2bf(rpb[((size_t)l * 961 + idx) * 8 + h]);
  }
  *(uint4*)(biasb + ((size_t)tid << 3)) = *(uint4*)o;
}

// ---------------- LN1 + shift + window partition -> bf16 wins ---------------
__global__ __launch_bounds__(256) void ln_part(const float* __restrict__ x,
                                               const float* __restrict__ g,
                                               const float* __restrict__ b,
                                               u16* __restrict__ out, int shift) {
  int wv = threadIdx.x >> 6, lane = threadIdx.x & 63;
  int wtok = blockIdx.x * 4 + wv;
  int w = wtok >> 8, t = wtok & 255;
  int bimg = w >> 4, wi = w & 15;
  int ph = (((wi >> 2) << 4) + (t >> 4) + shift) & 63;
  int pw = (((wi & 3) << 4) + (t & 15) + shift) & 63;
  const float4 v = *(const float4*)(x + ((size_t)((bimg * 64 + ph) * 64 + pw)) * 256 + lane * 4);
  float s = v.x + v.y + v.z + v.w;
  float sq = v.x * v.x + v.y * v.y + v.z * v.z + v.w * v.w;
  #pragma unroll
  for (int m = 1; m < 64; m <<= 1) { s += __shfl_xor(s, m, 64); sq += __shfl_xor(sq, m, 64); }
  float mean = s * (1.f / 256.f);
  float var = sq * (1.f / 256.f) - mean * mean;
  float rs = rsqrtf(var + 1e-5f);
  float4 gg = *(const float4*)(g + lane * 4);
  float4 bb = *(const float4*)(b + lane * 4);
  u16 o0 = f2bf((v.x - mean) * rs * gg.x + bb.x);
  u16 o1 = f2bf((v.y - mean) * rs * gg.y + bb.y);
  u16 o2 = f2bf((v.z - mean) * rs * gg.z + bb.z);
  u16 o3 = f2bf((v.w - mean) * rs * gg.w + bb.w);
  uint2 pk; pk.x = (unsigned)o0 | ((unsigned)o1 << 16); pk.y = (unsigned)o2 | ((unsigned)o3 << 16);
  *(uint2*)(out + (size_t)wtok * 256 + lane * 4) = pk;
}

// ---------------- GEMM, full-K staged: A[Mx256] bf16, B = L2 fragments ------
// 512 threads (8 waves, 2m x 4n). Whole 128x256 A-tile staged once via
// global_load_lds (64 KB, [kb][row][32] layout), ONE barrier, then 64 MFMA
// per wave with zero sync points. 2 blocks/CU = 16 waves/CU.
struct EpiParams {
  const float* bias;
  u16* obf;
  float* of32;
  const float* resid;
  int shift;
  float qscale;
};

// EPI: 0=qkv(bias,q-scale,bf16)  2=proj(bias,window-reverse+unshift+resid -> f32)
template <int EPI>
__global__ __launch_bounds__(512, 2) void gemm_fk(const u16* __restrict__ A,
                                                  const u16* __restrict__ Wf,
                                                  int N, EpiParams ep) {
  __shared__ u16 As[8][128][32];   // 64 KB
  int tid = threadIdx.x;
  int n0 = blockIdx.x * 128, m0 = blockIdx.y * 128;
  int wv = tid >> 6, lane = tid & 63, quad = lane >> 4, l15 = lane & 15;
  int wm = wv & 1, wn = wv >> 1;

  // stage whole A tile: 4096 x 16B chunks, lane-consecutive LDS destinations
  #pragma unroll
  for (int i = 0; i < 8; ++i) {
    int c = i * 512 + tid;
    int kb = c >> 9, rc = c & 511;
    int row = rc >> 2, kc = (rc & 3) * 8;
    GLDS16(A + (size_t)(m0 + row) * 256 + kb * 32 + kc, &As[kb][row][kc]);
  }
  __syncthreads();

  f32x4 acc[4][2] = {};
  #pragma unroll
  for (int kb = 0; kb < 8; ++kb) {
    short8 bf[2];
    #pragma unroll
    for (int nt = 0; nt < 2; ++nt) {
      size_t ntile = (size_t)(blockIdx.x * 8 + wn * 2 + nt);
      bf[nt] = *(const short8*)(Wf + ((ntile * 8 + kb) * 64 + lane) * 8);
    }
    #pragma unroll
    for (int mt = 0; mt < 4; ++mt) {
      short8 af = *(const short8*)&As[kb][wm * 64 + mt * 16 + l15][quad * 8];
      #pragma unroll
      for (int nt = 0; nt < 2; ++nt)
        acc[mt][nt] = __builtin_amdgcn_mfma_f32_16x16x32_bf16(af, bf[nt], acc[mt][nt], 0, 0, 0);
    }
  }

  #pragma unroll
  for (int mt = 0; mt < 4; ++mt) {
    #pragma unroll
    for (int nt = 0; nt < 2; ++nt) {
      #pragma unroll
      for (int r = 0; r < 4; ++r) {
        int grow = m0 + wm * 64 + mt * 16 + quad * 4 + r;
        int gcol = n0 + wn * 32 + nt * 16 + l15;
        float v = acc[mt][nt][r] + ep.bias[gcol];
        if constexpr (EPI == 0) {
          if (gcol < 256) v *= ep.qscale;
          ep.obf[(size_t)grow * N + gcol] = f2bf(v);
        } else {
          int w_ = grow >> 8, t = grow & 255, wi = w_ & 15;
          int ph = (((wi >> 2) << 4) + (t >> 4) + ep.shift) & 63;
          int pw = (((wi & 3) << 4) + (t & 15) + ep.shift) & 63;
          size_t pix = (size_t)(((w_ >> 4) * 64 + ph) * 64 + pw);
          ep.of32[pix * 256 + gcol] = ep.resid[pix * 256 + gcol] + v;
        }
      }
    }
  }
}

// ---------------- fused MLP v3: 512 threads (8 waves), 64-row tile ----------
__global__ __launch_bounds__(512, 4) void fused_mlp(const float* __restrict__ xin,
                                                    const float* __restrict__ g,
                                                    const float* __restrict__ b,
                                                    const u16* __restrict__ W1f,
                                                    const u16* __restrict__ W2f,
                                                    const float* __restrict__ b1p,
                                                    const float* __restrict__ b2p,
                                                    float* __restrict__ out) {
  __shared__ u16 Zs[64 * 264];
  __shared__ u16 Hs[2][64 * 136];
  int tid = threadIdx.x, wv = tid >> 6, lane = tid & 63;
  int quad = lane >> 4, l15 = lane & 15;
  int m0 = blockIdx.x * 64;

  float4 gg = *(const float4*)(g + lane * 4);
  float4 bb = *(const float4*)(b + lane * 4);
  #pragma unroll
  for (int rr = 0; rr < 8; ++rr) {
    int row = wv * 8 + rr;
    const float4 v = *(const float4*)(xin + (size_t)(m0 + row) * 256 + lane * 4);
    float s = v.x + v.y + v.z + v.w;
    float sq = v.x * v.x + v.y * v.y + v.z * v.z + v.w * v.w;
    #pragma unroll
    for (int m = 1; m < 64; m <<= 1) { s += __shfl_xor(s, m, 64); sq += __shfl_xor(sq, m, 64); }
    float mean = s * (1.f / 256.f);
    float var = sq * (1.f / 256.f) - mean * mean;
    float rs = rsqrtf(var + 1e-5f);
    u16 o0 = f2bf((v.x - mean) * rs * gg.x + bb.x);
    u16 o1 = f2bf((v.y - mean) * rs * gg.y + bb.y);
    u16 o2 = f2bf((v.z - mean) * rs * gg.z + bb.z);
    u16 o3 = f2bf((v.w - mean) * rs * gg.w + bb.w);
    uint2 pk; pk.x = (unsigned)o0 | ((unsigned)o1 << 16); pk.y = (unsigned)o2 | ((unsigned)o3 << 16);
    *(uint2*)&Zs[row * 264 + lane * 4] = pk;
  }
  __syncthreads();

  f32x4 acc2[4][2];
  #pragma unroll
  for (int nt = 0; nt < 2; ++nt) {
    float b2 = b2p[wv * 32 + nt * 16 + l15];
    #pragma unroll
    for (int mt = 0; mt < 4; ++mt)
      #pragma unroll
      for (int r = 0; r < 4; ++r) acc2[mt][nt][r] = b2;
  }

  for (int hc = 0; hc < 8; ++hc) {
    f32x4 acc1[4];
    {
      float b1 = b1p[hc * 128 + wv * 16 + l15];
      #pragma unroll
      for (int mt = 0; mt < 4; ++mt)
        #pragma unroll
        for (int r = 0; r < 4; ++r) acc1[mt][r] = b1;
    }
    #pragma unroll
    for (int ks = 0; ks < 8; ++ks) {
      short8 bf = *(const short8*)(W1f + ((((size_t)hc * 8 + ks) * 8 + wv) * 64 + lane) * 8);
      #pragma unroll
      for (int mt = 0; mt < 4; ++mt) {
        short8 af = *(const short8*)&Zs[(mt * 16 + l15) * 264 + ks * 32 + quad * 8];
        acc1[mt] = __builtin_amdgcn_mfma_f32_16x16x32_bf16(af, bf, acc1[mt], 0, 0, 0);
      }
    }
    u16* hs = &Hs[hc & 1][0];
    #pragma unroll
    for (int mt = 0; mt < 4; ++mt)
      #pragma unroll
      for (int r = 0; r < 4; ++r) {
        float v = acc1[mt][r];
        float inner = v * (1.f + 0.044715f * v * v);
        float e = __expf(-1.5957691216057308f * inner);
        float gl = v * __builtin_amdgcn_rcpf(1.f + e);
        hs[(mt * 16 + quad * 4 + r) * 136 + wv * 16 + l15] = f2bf(gl);
      }
    __syncthreads();
    #pragma unroll
    for (int ks = 0; ks < 4; ++ks) {
      short8 bf2[2];
      #pragma unroll
      for (int nt = 0; nt < 2; ++nt)
        bf2[nt] = *(const short8*)(W2f + ((((size_t)hc * 4 + ks) * 16 + wv * 2 + nt) * 64 + lane) * 8);
      #pragma unroll
      for (int mt = 0; mt < 4; ++mt) {
        short8 af2 = *(const short8*)&hs[(mt * 16 + l15) * 136 + ks * 32 + quad * 8];
        #pragma unroll
        for (int nt = 0; nt < 2; ++nt)
          acc2[mt][nt] = __builtin_amdgcn_mfma_f32_16x16x32_bf16(af2, bf2[nt], acc2[mt][nt], 0, 0, 0);
      }
    }
  }

  #pragma unroll
  for (int mt = 0; mt < 4; ++mt)
    #pragma unroll
    for (int nt = 0; nt < 2; ++nt)
      #pragma unroll
      for (int r = 0; r < 4; ++r) {
        size_t idx = (size_t)(m0 + mt * 16 + quad * 4 + r) * 256 + wv * 32 + nt * 16 + l15;
        out[idx] = xin[idx] + acc2[mt][nt][r];
      }
}

// ---------------- fused window attention v3 (unchanged) ---------------------
__global__ __launch_bounds__(256, 4) void attn_v3(const u16* __restrict__ qkv,
                                                  const u16* __restrict__ biasb,
                                                  int layer, u16* __restrict__ aout) {
  __shared__ u16 Klds[256 * 32];
  __shared__ u16 Vt[32 * 264];
  __shared__ u16 Plds[4][16 * 40];
  int bid = blockIdx.x;
  int lw = ((bid & 7) << 7) | (bid >> 3);   // XCD swizzle
  int w = lw >> 3, h = lw & 7;
  int tid = threadIdx.x;

  {
    const uint4* kp = (const uint4*)(qkv + ((size_t)(w * 256 + tid)) * 768 + 256 + h * 32);
    uint4* kd = (uint4*)&Klds[tid * 32];
    kd[0] = kp[0]; kd[1] = kp[1]; kd[2] = kp[2]; kd[3] = kp[3];
    const uint4* vp = (const uint4*)(qkv + ((size_t)(w * 256 + tid)) * 768 + 512 + h * 32);
    u16 vt[32];
    *(uint4*)&vt[0]  = vp[0];
    *(uint4*)&vt[8]  = vp[1];
    *(uint4*)&vt[16] = vp[2];
    *(uint4*)&vt[24] = vp[3];
    #pragma unroll
    for (int d = 0; d < 32; ++d) Vt[d * 264 + tid] = vt[d];
  }
  __syncthreads();

  int wv = tid >> 6, lane = tid & 63, quad = lane >> 4, l15 = lane & 15;
  int wi = w & 15, wr = wi >> 2, wc = wi & 3;
  const bool masked = (layer != 0) && (wr == 3 || wc == 3);
  int rcj = (wc == 3) ? (l15 < 8 ? 1 : 2) : 0;

  #pragma unroll
  for (int mt = 0; mt < 4; ++mt) {
    int mslot = wv * 4 + mt;
    int m0 = mslot * 16;
    short8 aq = *(const short8*)(qkv + ((size_t)(w * 256 + m0 + l15)) * 768 + h * 32 + quad * 8);
    const u16* bmt = biasb + ((size_t)layer << 19) + ((size_t)h << 16) + (size_t)mslot * 4096;
    f32x4 c[16];
    #pragma unroll
    for (int k = 0; k < 8; ++k) {
      short8 bv = *(const short8*)(bmt + k * 512 + lane * 8);
      #pragma unroll
      for (int r = 0; r < 4; ++r) {
        c[2 * k][r]     = bf2f((u16)bv[r]);
        c[2 * k + 1][r] = bf2f((u16)bv[4 + r]);
      }
    }
    #pragma unroll
    for (int nt = 0; nt < 16; ++nt) {
      short8 bk = *(const short8*)&Klds[(nt * 16 + l15) * 32 + quad * 8];
      c[nt] = __builtin_amdgcn_mfma_f32_16x16x32_bf16(aq, bk, c[nt], 0, 0, 0);
    }
    if (masked) {
      int regi = ((wr == 3) ? (mslot < 8 ? 1 : 2) : 0) * 3 +
                 ((wc == 3) ? (quad < 2 ? 1 : 2) : 0);
      #pragma unroll
      for (int nt = 0; nt < 16; ++nt) {
        int regj = ((wr == 3) ? (nt < 8 ? 1 : 2) : 0) * 3 + rcj;
        float madd = (regi != regj) ? -100.f : 0.f;
        #pragma unroll
        for (int r = 0; r < 4; ++r) c[nt][r] += madd;
      }
    }
    float pm[4] = {-1e30f, -1e30f, -1e30f, -1e30f};
    #pragma unroll
    for (int nt = 0; nt < 16; ++nt)
      #pragma unroll
      for (int r = 0; r < 4; ++r) pm[r] = fmaxf(pm[r], c[nt][r]);
    #pragma unroll
    for (int r = 0; r < 4; ++r) {
      pm[r] = fmaxf(pm[r], __shfl_xor(pm[r], 1, 64));
      pm[r] = fmaxf(pm[r], __shfl_xor(pm[r], 2, 64));
      pm[r] = fmaxf(pm[r], __shfl_xor(pm[r], 4, 64));
      pm[r] = fmaxf(pm[r], __shfl_xor(pm[r], 8, 64));
    }
    float psum[4] = {0.f, 0.f, 0.f, 0.f};
    #pragma unroll
    for (int nt = 0; nt < 16; ++nt)
      #pragma unroll
      for (int r = 0; r < 4; ++r) {
        float e = __expf(c[nt][r] - pm[r]);
        c[nt][r] = e;
        psum[r] += e;
      }
    #pragma unroll
    for (int r = 0; r < 4; ++r) {
      psum[r] += __shfl_xor(psum[r], 1, 64);
      psum[r] += __shfl_xor(psum[r], 2, 64);
      psum[r] += __shfl_xor(psum[r], 4, 64);
      psum[r] += __shfl_xor(psum[r], 8, 64);
    }
    f32x4 o0 = {0.f, 0.f, 0.f, 0.f}, o1 = {0.f, 0.f, 0.f, 0.f};
    #pragma unroll
    for (int kk = 0; kk < 8; ++kk) {
      #pragma unroll
      for (int r = 0; r < 4; ++r) {
        Plds[wv][(quad * 4 + r) * 40 + l15] = f2bf(c[2 * kk][r]);
        Plds[wv][(quad * 4 + r) * 40 + 16 + l15] = f2bf(c[2 * kk + 1][r]);
      }
      short8 ap = *(const short8*)&Plds[wv][l15 * 40 + quad * 8];
      short8 bv0 = *(const short8*)&Vt[l15 * 264 + kk * 32 + quad * 8];
      short8 bv1 = *(const short8*)&Vt[(16 + l15) * 264 + kk * 32 + quad * 8];
      o0 = __builtin_amdgcn_mfma_f32_16x16x32_bf16(ap, bv0, o0, 0, 0, 0);
      o1 = __builtin_amdgcn_mfma_f32_16x16x32_bf16(ap, bv1, o1, 0, 0, 0);
    }
    #pragma unroll
    for (int r = 0; r < 4; ++r) {
      float inv = 1.f / psum[r];
      size_t row = (size_t)(w * 256 + m0 + quad * 4 + r);
      aout[row * 256 + h * 32 + l15] = f2bf(o0[r] * inv);
      aout[row * 256 + h * 32 + 16 + l15] = f2bf(o1[r] * inv);
    }
  }
}

// ----------------------------------------------------------------------------
extern "C" void kernel_launch(void* const* d_in, const int* in_sizes, int n_in,
                              void* d_out, int out_size, void* d_ws, size_t ws_size,
                              hipStream_t stream) {
  const float* x      = (const float*)d_in[0];
  const float* ln1_g  = (const float*)d_in[1];
  const float* ln1_b  = (const float*)d_in[2];
  const float* qkv_w  = (const float*)d_in[3];
  const float* qkv_b  = (const float*)d_in[4];
  const float* rpb    = (const float*)d_in[5];
  const float* proj_w = (const float*)d_in[6];
  const float* proj_b = (const float*)d_in[7];
  const float* ln2_g  = (const float*)d_in[8];
  const float* ln2_b  = (const float*)d_in[9];
  const float* fc1_w  = (const float*)d_in[10];
  const float* fc1_b  = (const float*)d_in[11];
  const float* fc2_w  = (const float*)d_in[12];
  const float* fc2_b  = (const float*)d_in[13];
  const int*   rpi    = (const int*)d_in[15];

  char* ws = (char*)d_ws;
  size_t off = 0;
  auto alloc = [&](size_t bytes) { void* p = ws + off; off += (bytes + 255) & ~(size_t)255; return p; };
  float* x_cur   = (float*)alloc((size_t)32768 * 256 * 4);   // residual stream
  u16* sbuf      = (u16*)alloc((size_t)32768 * 256 * 2);     // wins -> attn_out
  u16* qkvb      = (u16*)alloc((size_t)32768 * 768 * 2);
  u16* biasb     = (u16*)alloc((size_t)2 * 8 * 65536 * 2);   // pre-swizzled bf16 bias
  u16* qkvF      = (u16*)alloc((size_t)2 * 196608 * 2);      // qkv B-fragments
  u16* projF     = (u16*)alloc((size_t)2 * 65536 * 2);       // proj B-fragments
  u16* W1f       = (u16*)alloc((size_t)2 * 262144 * 2);      // fc1 B-fragments
  u16* W2f       = (u16*)alloc((size_t)2 * 262144 * 2);      // fc2 B-fragments

  // prep
  wswizB<<<192, 256, 0, stream>>>(qkv_w, qkvF, 256, 768);
  wswizB<<<64, 256, 0, stream>>>(proj_w, projF, 256, 256);
  wswiz1<<<256, 256, 0, stream>>>(fc1_w, W1f);
  wswiz2<<<256, 256, 0, stream>>>(fc2_w, W2f);
  bias_gb<<<512, 256, 0, stream>>>(rpb, rpi, biasb);

  for (int i = 0; i < 2; ++i) {
    int shift = i ? 8 : 0;
    const float* xin = i ? x_cur : x;

    ln_part<<<8192, 256, 0, stream>>>(xin, ln1_g + i * 256, ln1_b + i * 256, sbuf, shift);

    EpiParams ep{};
    ep.bias = qkv_b + i * 768; ep.obf = qkvb; ep.qscale = 0.17677669529663687f;
    gemm_fk<0><<<dim3(6, 256), 512, 0, stream>>>(sbuf, qkvF + (size_t)i * 196608, 768, ep);

    attn_v3<<<1024, 256, 0, stream>>>(qkvb, biasb, i, sbuf);

    ep = EpiParams{};
    ep.bias = proj_b + i * 256; ep.of32 = x_cur; ep.resid = xin; ep.shift = shift;
    gemm_fk<2><<<dim3(2, 256), 512, 0, stream>>>(sbuf, projF + (size_t)i * 65536, 256, ep);

    fused_mlp<<<512, 512, 0, stream>>>(x_cur, ln2_g + i * 256, ln2_b + i * 256,
                                       W1f + (size_t)i * 262144, W2f + (size_t)i * 262144,
                                       fc1_b + i * 1024, fc2_b + i * 256,
                                       (i == 1) ? (float*)d_out : x_cur);
  }
}

// Round 8
// 405.179 us; speedup vs baseline: 1.3682x; 1.0455x over previous
//
#include <hip/hip_runtime.h>

typedef unsigned short u16;
typedef __attribute__((ext_vector_type(8))) short short8;
typedef __attribute__((ext_vector_type(4))) float f32x4;

#define GLDS16(gp, sp) __builtin_amdgcn_global_load_lds( \
    (const __attribute__((address_space(1))) void*)(gp),  \
    (__attribute__((address_space(3))) void*)(sp), 16, 0, 0)

__device__ __forceinline__ u16 f2bf(float f) {
  union { float f; unsigned u; } x; x.f = f;
  unsigned r = (x.u + 0x7fffu + ((x.u >> 16) & 1u)) >> 16;  // RNE
  return (u16)r;
}
__device__ __forceinline__ float bf2f(u16 v) {
  union { unsigned u; float f; } x; x.u = ((unsigned)v) << 16; return x.f;
}

// ------- generic weight -> bf16 MFMA B-fragment order --------------------
__global__ __launch_bounds__(256) void wswizB(const float* __restrict__ W,
                                              u16* __restrict__ Wf, int K, int N) {
  int tid = blockIdx.x * 256 + threadIdx.x;
  int Kt = K >> 5, Nt = N >> 4;
  int per = Nt * Kt * 64;
  if (tid >= 2 * per) return;
  int l = tid >= per;
  int rem = tid - l * per;
  int nb = rem / (Kt * 64);
  int rem2 = rem - nb * Kt * 64;
  int ks = rem2 >> 6, lane = rem2 & 63;
  int n = nb * 16 + (lane & 15);
  u16 o[8];
  #pragma unroll
  for (int e = 0; e < 8; ++e) {
    int k = ks * 32 + ((lane >> 4) << 3) + e;
    o[e] = f2bf(W[((size_t)l * K + k) * N + n]);
  }
  *(uint4*)(Wf + ((size_t)tid << 3)) = *(uint4*)o;
}

// ------- fc1 weights -> B-fragment order: W1f[l][hc(8)][ks(8)][ntile(8)][lane][8]
__global__ __launch_bounds__(256) void wswiz1(const float* __restrict__ W,
                                              u16* __restrict__ Wf) {
  int tid = blockIdx.x * 256 + threadIdx.x;  // [0, 65536)
  int lane = tid & 63, nt = (tid >> 6) & 7, ks = (tid >> 9) & 7,
      hc = (tid >> 12) & 7, l = tid >> 15;
  int n = hc * 128 + nt * 16 + (lane & 15);
  u16 o[8];
  #pragma unroll
  for (int e = 0; e < 8; ++e) {
    int k = ks * 32 + ((lane >> 4) << 3) + e;
    o[e] = f2bf(W[((size_t)l * 256 + k) * 1024 + n]);
  }
  *(uint4*)(Wf + ((size_t)tid << 3)) = *(uint4*)o;
}

// ------- fc2 weights -> B-fragment order: W2f[l][hc(8)][ks(4)][ntile(16)][lane][8]
__global__ __launch_bounds__(256) void wswiz2(const float* __restrict__ W,
                                              u16* __restrict__ Wf) {
  int tid = blockIdx.x * 256 + threadIdx.x;  // [0, 65536)
  int lane = tid & 63, nt = (tid >> 6) & 15, ks = (tid >> 10) & 3,
      hc = (tid >> 12) & 7, l = tid >> 15;
  int n = nt * 16 + (lane & 15);
  u16 o[8];
  #pragma unroll
  for (int e = 0; e < 8; ++e) {
    int k = hc * 128 + ks * 32 + ((lane >> 4) << 3) + e;
    o[e] = f2bf(W[((size_t)l * 1024 + k) * 256 + n]);
  }
  *(uint4*)(Wf + ((size_t)tid << 3)) = *(uint4*)o;
}

// ------- rel-pos bias gather, bf16, pre-swizzled to MFMA C-layout ------------
__global__ __launch_bounds__(256) void bias_gb(const float* __restrict__ rpb,
                                               const int* __restrict__ rpi,
                                               u16* __restrict__ biasb) {
  int tid = blockIdx.x * 256 + threadIdx.x;  // [0, 2*65536)
  if (tid >= 131072) return;
  int l = tid >> 16, cid = tid & 65535;
  int lane = cid & 63, k = (cid >> 6) & 7, mslot = (cid >> 9) & 15, h = cid >> 13;
  u16 o[8];
  #pragma unroll
  for (int e = 0; e < 8; ++e) {
    int nt = 2 * k + (e >> 2), r = e & 3;
    int i = mslot * 16 + ((lane >> 4) << 2) + r;
    int j = nt * 16 + (lane & 15);
    int idx = rpi[i * 256 + j];
    o[e] = f2bf(rpb[((size_t)l * 961 + idx) * 8 + h]);
  }
  *(uint4*)(biasb + ((size_t)tid << 3)) = *(uint4*)o;
}

// ---------------- LN1 + shift + window partition -> bf16 wins ---------------
__global__ __launch_bounds__(256) void ln_part(const float* __restrict__ x,
                                               const float* __restrict__ g,
                                               const float* __restrict__ b,
                                               u16* __restrict__ out, int shift) {
  int wv = threadIdx.x >> 6, lane = threadIdx.x & 63;
  int wtok = blockIdx.x * 4 + wv;
  int w = wtok >> 8, t = wtok & 255;
  int bimg = w >> 4, wi = w & 15;
  int ph = (((wi >> 2) << 4) + (t >> 4) + shift) & 63;
  int pw = (((wi & 3) << 4) + (t & 15) + shift) & 63;
  const float4 v = *(const float4*)(x + ((size_t)((bimg * 64 + ph) * 64 + pw)) * 256 + lane * 4);
  float s = v.x + v.y + v.z + v.w;
  float sq = v.x * v.x + v.y * v.y + v.z * v.z + v.w * v.w;
  #pragma unroll
  for (int m = 1; m < 64; m <<= 1) { s += __shfl_xor(s, m, 64); sq += __shfl_xor(sq, m, 64); }
  float mean = s * (1.f / 256.f);
  float var = sq * (1.f / 256.f) - mean * mean;
  float rs = rsqrtf(var + 1e-5f);
  float4 gg = *(const float4*)(g + lane * 4);
  float4 bb = *(const float4*)(b + lane * 4);
  u16 o0 = f2bf((v.x - mean) * rs * gg.x + bb.x);
  u16 o1 = f2bf((v.y - mean) * rs * gg.y + bb.y);
  u16 o2 = f2bf((v.z - mean) * rs * gg.z + bb.z);
  u16 o3 = f2bf((v.w - mean) * rs * gg.w + bb.w);
  uint2 pk; pk.x = (unsigned)o0 | ((unsigned)o1 << 16); pk.y = (unsigned)o2 | ((unsigned)o3 << 16);
  *(uint2*)(out + (size_t)wtok * 256 + lane * 4) = pk;
}

struct EpiParams {
  const float* bias;
  u16* obf;
  float* of32;
  const float* resid;
  int shift;
  float qscale;
};

// ---------------- GEMM v2: 128x256 tile, full-K staged, A-read reuse x4 -----
// 8 waves as 2m x 4n; wave owns 4mt x 4nt: 4 LDS A-reads serve 16 MFMA.
__global__ __launch_bounds__(512, 2) void gemm_fk2(const u16* __restrict__ A,
                                                   const u16* __restrict__ Wf,
                                                   int N, EpiParams ep) {
  __shared__ u16 As[8][128][32];   // 64 KB
  int tid = threadIdx.x;
  int n0 = blockIdx.x * 256, m0 = blockIdx.y * 128;
  int wv = tid >> 6, lane = tid & 63, quad = lane >> 4, l15 = lane & 15;
  int wm = wv & 1, wn = wv >> 1;   // wn in 0..3

  #pragma unroll
  for (int i = 0; i < 8; ++i) {
    int c = i * 512 + tid;
    int kb = c >> 9, rc = c & 511;
    int row = rc >> 2, kc = (rc & 3) * 8;
    GLDS16(A + (size_t)(m0 + row) * 256 + kb * 32 + kc, &As[kb][row][kc]);
  }
  __syncthreads();

  f32x4 acc[4][4] = {};
  #pragma unroll
  for (int kb = 0; kb < 8; ++kb) {
    short8 bf[4];
    #pragma unroll
    for (int nt = 0; nt < 4; ++nt) {
      size_t ntile = (size_t)(blockIdx.x * 16 + wn * 4 + nt);
      bf[nt] = *(const short8*)(Wf + ((ntile * 8 + kb) * 64 + lane) * 8);
    }
    #pragma unroll
    for (int mt = 0; mt < 4; ++mt) {
      short8 af = *(const short8*)&As[kb][wm * 64 + mt * 16 + l15][quad * 8];
      #pragma unroll
      for (int nt = 0; nt < 4; ++nt)
        acc[mt][nt] = __builtin_amdgcn_mfma_f32_16x16x32_bf16(af, bf[nt], acc[mt][nt], 0, 0, 0);
    }
  }

  #pragma unroll
  for (int mt = 0; mt < 4; ++mt) {
    #pragma unroll
    for (int nt = 0; nt < 4; ++nt) {
      #pragma unroll
      for (int r = 0; r < 4; ++r) {
        int grow = m0 + wm * 64 + mt * 16 + quad * 4 + r;
        int gcol = n0 + wn * 64 + nt * 16 + l15;
        float v = acc[mt][nt][r] + ep.bias[gcol];
        if (gcol < 256) v *= ep.qscale;
        ep.obf[(size_t)grow * N + gcol] = f2bf(v);
      }
    }
  }
}

// ---------------- GEMM, full-K staged (round-7, used for proj) --------------
template <int EPI>
__global__ __launch_bounds__(512, 2) void gemm_fk(const u16* __restrict__ A,
                                                  const u16* __restrict__ Wf,
                                                  int N, EpiParams ep) {
  __shared__ u16 As[8][128][32];   // 64 KB
  int tid = threadIdx.x;
  int n0 = blockIdx.x * 128, m0 = blockIdx.y * 128;
  int wv = tid >> 6, lane = tid & 63, quad = lane >> 4, l15 = lane & 15;
  int wm = wv & 1, wn = wv >> 1;

  #pragma unroll
  for (int i = 0; i < 8; ++i) {
    int c = i * 512 + tid;
    int kb = c >> 9, rc = c & 511;
    int row = rc >> 2, kc = (rc & 3) * 8;
    GLDS16(A + (size_t)(m0 + row) * 256 + kb * 32 + kc, &As[kb][row][kc]);
  }
  __syncthreads();

  f32x4 acc[4][2] = {};
  #pragma unroll
  for (int kb = 0; kb < 8; ++kb) {
    short8 bf[2];
    #pragma unroll
    for (int nt = 0; nt < 2; ++nt) {
      size_t ntile = (size_t)(blockIdx.x * 8 + wn * 2 + nt);
      bf[nt] = *(const short8*)(Wf + ((ntile * 8 + kb) * 64 + lane) * 8);
    }
    #pragma unroll
    for (int mt = 0; mt < 4; ++mt) {
      short8 af = *(const short8*)&As[kb][wm * 64 + mt * 16 + l15][quad * 8];
      #pragma unroll
      for (int nt = 0; nt < 2; ++nt)
        acc[mt][nt] = __builtin_amdgcn_mfma_f32_16x16x32_bf16(af, bf[nt], acc[mt][nt], 0, 0, 0);
    }
  }

  #pragma unroll
  for (int mt = 0; mt < 4; ++mt) {
    #pragma unroll
    for (int nt = 0; nt < 2; ++nt) {
      #pragma unroll
      for (int r = 0; r < 4; ++r) {
        int grow = m0 + wm * 64 + mt * 16 + quad * 4 + r;
        int gcol = n0 + wn * 32 + nt * 16 + l15;
        float v = acc[mt][nt][r] + ep.bias[gcol];
        if constexpr (EPI == 0) {
          if (gcol < 256) v *= ep.qscale;
          ep.obf[(size_t)grow * N + gcol] = f2bf(v);
        } else {
          int w_ = grow >> 8, t = grow & 255, wi = w_ & 15;
          int ph = (((wi >> 2) << 4) + (t >> 4) + ep.shift) & 63;
          int pw = (((wi & 3) << 4) + (t & 15) + ep.shift) & 63;
          size_t pix = (size_t)(((w_ >> 4) * 64 + ph) * 64 + pw);
          ep.of32[pix * 256 + gcol] = ep.resid[pix * 256 + gcol] + v;
        }
      }
    }
  }
}

// ---------------- fused MLP v4: hc-pairing (phase-A LDS reads halved) -------
__global__ __launch_bounds__(512, 4) void fused_mlp(const float* __restrict__ xin,
                                                    const float* __restrict__ g,
                                                    const float* __restrict__ b,
                                                    const u16* __restrict__ W1f,
                                                    const u16* __restrict__ W2f,
                                                    const float* __restrict__ b1p,
                                                    const float* __restrict__ b2p,
                                                    float* __restrict__ out) {
  __shared__ u16 Zs[64 * 264];
  __shared__ u16 Hs[2][64 * 136];
  int tid = threadIdx.x, wv = tid >> 6, lane = tid & 63;
  int quad = lane >> 4, l15 = lane & 15;
  int m0 = blockIdx.x * 64;

  float4 gg = *(const float4*)(g + lane * 4);
  float4 bb = *(const float4*)(b + lane * 4);
  #pragma unroll
  for (int rr = 0; rr < 8; ++rr) {
    int row = wv * 8 + rr;
    const float4 v = *(const float4*)(xin + (size_t)(m0 + row) * 256 + lane * 4);
    float s = v.x + v.y + v.z + v.w;
    float sq = v.x * v.x + v.y * v.y + v.z * v.z + v.w * v.w;
    #pragma unroll
    for (int m = 1; m < 64; m <<= 1) { s += __shfl_xor(s, m, 64); sq += __shfl_xor(sq, m, 64); }
    float mean = s * (1.f / 256.f);
    float var = sq * (1.f / 256.f) - mean * mean;
    float rs = rsqrtf(var + 1e-5f);
    u16 o0 = f2bf((v.x - mean) * rs * gg.x + bb.x);
    u16 o1 = f2bf((v.y - mean) * rs * gg.y + bb.y);
    u16 o2 = f2bf((v.z - mean) * rs * gg.z + bb.z);
    u16 o3 = f2bf((v.w - mean) * rs * gg.w + bb.w);
    uint2 pk; pk.x = (unsigned)o0 | ((unsigned)o1 << 16); pk.y = (unsigned)o2 | ((unsigned)o3 << 16);
    *(uint2*)&Zs[row * 264 + lane * 4] = pk;
  }
  __syncthreads();

  f32x4 acc2[4][2];
  #pragma unroll
  for (int nt = 0; nt < 2; ++nt) {
    float b2 = b2p[wv * 32 + nt * 16 + l15];
    #pragma unroll
    for (int mt = 0; mt < 4; ++mt)
      #pragma unroll
      for (int r = 0; r < 4; ++r) acc2[mt][nt][r] = b2;
  }

  for (int hp = 0; hp < 4; ++hp) {
    int hcA = 2 * hp, hcB = 2 * hp + 1;
    // ---- phase A for BOTH chunks, sharing Zs fragment reads
    f32x4 acc1a[4], acc1b[4];
    {
      float b1a = b1p[hcA * 128 + wv * 16 + l15];
      float b1b = b1p[hcB * 128 + wv * 16 + l15];
      #pragma unroll
      for (int mt = 0; mt < 4; ++mt)
        #pragma unroll
        for (int r = 0; r < 4; ++r) { acc1a[mt][r] = b1a; acc1b[mt][r] = b1b; }
    }
    #pragma unroll
    for (int ks = 0; ks < 8; ++ks) {
      short8 bfa = *(const short8*)(W1f + ((((size_t)hcA * 8 + ks) * 8 + wv) * 64 + lane) * 8);
      short8 bfb = *(const short8*)(W1f + ((((size_t)hcB * 8 + ks) * 8 + wv) * 64 + lane) * 8);
      #pragma unroll
      for (int mt = 0; mt < 4; ++mt) {
        short8 af = *(const short8*)&Zs[(mt * 16 + l15) * 264 + ks * 32 + quad * 8];
        acc1a[mt] = __builtin_amdgcn_mfma_f32_16x16x32_bf16(af, bfa, acc1a[mt], 0, 0, 0);
        acc1b[mt] = __builtin_amdgcn_mfma_f32_16x16x32_bf16(af, bfb, acc1b[mt], 0, 0, 0);
      }
    }
    // ---- gelu + transpose both chunks
    #pragma unroll
    for (int mt = 0; mt < 4; ++mt)
      #pragma unroll
      for (int r = 0; r < 4; ++r) {
        float va = acc1a[mt][r];
        float ia = va * (1.f + 0.044715f * va * va);
        float ea = __expf(-1.5957691216057308f * ia);
        Hs[0][(mt * 16 + quad * 4 + r) * 136 + wv * 16 + l15] =
            f2bf(va * __builtin_amdgcn_rcpf(1.f + ea));
        float vb = acc1b[mt][r];
        float ib = vb * (1.f + 0.044715f * vb * vb);
        float eb = __expf(-1.5957691216057308f * ib);
        Hs[1][(mt * 16 + quad * 4 + r) * 136 + wv * 16 + l15] =
            f2bf(vb * __builtin_amdgcn_rcpf(1.f + eb));
      }
    __syncthreads();
    // ---- phase B over both chunks
    #pragma unroll
    for (int buf = 0; buf < 2; ++buf) {
      int hc = 2 * hp + buf;
      #pragma unroll
      for (int ks = 0; ks < 4; ++ks) {
        short8 bf2[2];
        #pragma unroll
        for (int nt = 0; nt < 2; ++nt)
          bf2[nt] = *(const short8*)(W2f + ((((size_t)hc * 4 + ks) * 16 + wv * 2 + nt) * 64 + lane) * 8);
        #pragma unroll
        for (int mt = 0; mt < 4; ++mt) {
          short8 af2 = *(const short8*)&Hs[buf][(mt * 16 + l15) * 136 + ks * 32 + quad * 8];
          #pragma unroll
          for (int nt = 0; nt < 2; ++nt)
            acc2[mt][nt] = __builtin_amdgcn_mfma_f32_16x16x32_bf16(af2, bf2[nt], acc2[mt][nt], 0, 0, 0);
        }
      }
    }
    __syncthreads();
  }

  #pragma unroll
  for (int mt = 0; mt < 4; ++mt)
    #pragma unroll
    for (int nt = 0; nt < 2; ++nt)
      #pragma unroll
      for (int r = 0; r < 4; ++r) {
        size_t idx = (size_t)(m0 + mt * 16 + quad * 4 + r) * 256 + wv * 32 + nt * 16 + l15;
        out[idx] = xin[idx] + acc2[mt][nt][r];
      }
}

// ---------------- fused window attention v3 (unchanged) ---------------------
__global__ __launch_bounds__(256, 4) void attn_v3(const u16* __restrict__ qkv,
                                                  const u16* __restrict__ biasb,
                                                  int layer, u16* __restrict__ aout) {
  __shared__ u16 Klds[256 * 32];
  __shared__ u16 Vt[32 * 264];
  __shared__ u16 Plds[4][16 * 40];
  int bid = blockIdx.x;
  int lw = ((bid & 7) << 7) | (bid >> 3);   // XCD swizzle
  int w = lw >> 3, h = lw & 7;
  int tid = threadIdx.x;

  {
    const uint4* kp = (const uint4*)(qkv + ((size_t)(w * 256 + tid)) * 768 + 256 + h * 32);
    uint4* kd = (uint4*)&Klds[tid * 32];
    kd[0] = kp[0]; kd[1] = kp[1]; kd[2] = kp[2]; kd[3] = kp[3];
    const uint4* vp = (const uint4*)(qkv + ((size_t)(w * 256 + tid)) * 768 + 512 + h * 32);
    u16 vt[32];
    *(uint4*)&vt[0]  = vp[0];
    *(uint4*)&vt[8]  = vp[1];
    *(uint4*)&vt[16] = vp[2];
    *(uint4*)&vt[24] = vp[3];
    #pragma unroll
    for (int d = 0; d < 32; ++d) Vt[d * 264 + tid] = vt[d];
  }
  __syncthreads();

  int wv = tid >> 6, lane = tid & 63, quad = lane >> 4, l15 = lane & 15;
  int wi = w & 15, wr = wi >> 2, wc = wi & 3;
  const bool masked = (layer != 0) && (wr == 3 || wc == 3);
  int rcj = (wc == 3) ? (l15 < 8 ? 1 : 2) : 0;

  #pragma unroll
  for (int mt = 0; mt < 4; ++mt) {
    int mslot = wv * 4 + mt;
    int m0 = mslot * 16;
    short8 aq = *(const short8*)(qkv + ((size_t)(w * 256 + m0 + l15)) * 768 + h * 32 + quad * 8);
    const u16* bmt = biasb + ((size_t)layer << 19) + ((size_t)h << 16) + (size_t)mslot * 4096;
    f32x4 c[16];
    #pragma unroll
    for (int k = 0; k < 8; ++k) {
      short8 bv = *(const short8*)(bmt + k * 512 + lane * 8);
      #pragma unroll
      for (int r = 0; r < 4; ++r) {
        c[2 * k][r]     = bf2f((u16)bv[r]);
        c[2 * k + 1][r] = bf2f((u16)bv[4 + r]);
      }
    }
    #pragma unroll
    for (int nt = 0; nt < 16; ++nt) {
      short8 bk = *(const short8*)&Klds[(nt * 16 + l15) * 32 + quad * 8];
      c[nt] = __builtin_amdgcn_mfma_f32_16x16x32_bf16(aq, bk, c[nt], 0, 0, 0);
    }
    if (masked) {
      int regi = ((wr == 3) ? (mslot < 8 ? 1 : 2) : 0) * 3 +
                 ((wc == 3) ? (quad < 2 ? 1 : 2) : 0);
      #pragma unroll
      for (int nt = 0; nt < 16; ++nt) {
        int regj = ((wr == 3) ? (nt < 8 ? 1 : 2) : 0) * 3 + rcj;
        float madd = (regi != regj) ? -100.f : 0.f;
        #pragma unroll
        for (int r = 0; r < 4; ++r) c[nt][r] += madd;
      }
    }
    float pm[4] = {-1e30f, -1e30f, -1e30f, -1e30f};
    #pragma unroll
    for (int nt = 0; nt < 16; ++nt)
      #pragma unroll
      for (int r = 0; r < 4; ++r) pm[r] = fmaxf(pm[r], c[nt][r]);
    #pragma unroll
    for (int r = 0; r < 4; ++r) {
      pm[r] = fmaxf(pm[r], __shfl_xor(pm[r], 1, 64));
      pm[r] = fmaxf(pm[r], __shfl_xor(pm[r], 2, 64));
      pm[r] = fmaxf(pm[r], __shfl_xor(pm[r], 4, 64));
      pm[r] = fmaxf(pm[r], __shfl_xor(pm[r], 8, 64));
    }
    float psum[4] = {0.f, 0.f, 0.f, 0.f};
    #pragma unroll
    for (int nt = 0; nt < 16; ++nt)
      #pragma unroll
      for (int r = 0; r < 4; ++r) {
        float e = __expf(c[nt][r] - pm[r]);
        c[nt][r] = e;
        psum[r] += e;
      }
    #pragma unroll
    for (int r = 0; r < 4; ++r) {
      psum[r] += __shfl_xor(psum[r], 1, 64);
      psum[r] += __shfl_xor(psum[r], 2, 64);
      psum[r] += __shfl_xor(psum[r], 4, 64);
      psum[r] += __shfl_xor(psum[r], 8, 64);
    }
    f32x4 o0 = {0.f, 0.f, 0.f, 0.f}, o1 = {0.f, 0.f, 0.f, 0.f};
    #pragma unroll
    for (int kk = 0; kk < 8; ++kk) {
      #pragma unroll
      for (int r = 0; r < 4; ++r) {
        Plds[wv][(quad * 4 + r) * 40 + l15] = f2bf(c[2 * kk][r]);
        Plds[wv][(quad * 4 + r) * 40 + 16 + l15] = f2bf(c[2 * kk + 1][r]);
      }
      short8 ap = *(const short8*)&Plds[wv][l15 * 40 + quad * 8];
      short8 bv0 = *(const short8*)&Vt[l15 * 264 + kk * 32 + quad * 8];
      short8 bv1 = *(const short8*)&Vt[(16 + l15) * 264 + kk * 32 + quad * 8];
      o0 = __builtin_amdgcn_mfma_f32_16x16x32_bf16(ap, bv0, o0, 0, 0, 0);
      o1 = __builtin_amdgcn_mfma_f32_16x16x32_bf16(ap, bv1, o1, 0, 0, 0);
    }
    #pragma unroll
    for (int r = 0; r < 4; ++r) {
      float inv = 1.f / psum[r];
      size_t row = (size_t)(w * 256 + m0 + quad * 4 + r);
      aout[row * 256 + h * 32 + l15] = f2bf(o0[r] * inv);
      aout[row * 256 + h * 32 + 16 + l15] = f2bf(o1[r] * inv);
    }
  }
}

// ----------------------------------------------------------------------------
extern "C" void kernel_launch(void* const* d_in, const int* in_sizes, int n_in,
                              void* d_out, int out_size, void* d_ws, size_t ws_size,
                              hipStream_t stream) {
  const float* x      = (const float*)d_in[0];
  const float* ln1_g  = (const float*)d_in[1];
  const float* ln1_b  = (const float*)d_in[2];
  const float* qkv_w  = (const float*)d_in[3];
  const float* qkv_b  = (const float*)d_in[4];
  const float* rpb    = (const float*)d_in[5];
  const float* proj_w = (const float*)d_in[6];
  const float* proj_b = (const float*)d_in[7];
  const float* ln2_g  = (const float*)d_in[8];
  const float* ln2_b  = (const float*)d_in[9];
  const float* fc1_w  = (const float*)d_in[10];
  const float* fc1_b  = (const float*)d_in[11];
  const float* fc2_w  = (const float*)d_in[12];
  const float* fc2_b  = (const float*)d_in[13];
  const int*   rpi    = (const int*)d_in[15];

  char* ws = (char*)d_ws;
  size_t off = 0;
  auto alloc = [&](size_t bytes) { void* p = ws + off; off += (bytes + 255) & ~(size_t)255; return p; };
  float* x_cur   = (float*)alloc((size_t)32768 * 256 * 4);   // residual stream
  u16* sbuf      = (u16*)alloc((size_t)32768 * 256 * 2);     // wins -> attn_out
  u16* qkvb      = (u16*)alloc((size_t)32768 * 768 * 2);
  u16* biasb     = (u16*)alloc((size_t)2 * 8 * 65536 * 2);   // pre-swizzled bf16 bias
  u16* qkvF      = (u16*)alloc((size_t)2 * 196608 * 2);      // qkv B-fragments
  u16* projF     = (u16*)alloc((size_t)2 * 65536 * 2);       // proj B-fragments
  u16* W1f       = (u16*)alloc((size_t)2 * 262144 * 2);      // fc1 B-fragments
  u16* W2f       = (u16*)alloc((size_t)2 * 262144 * 2);      // fc2 B-fragments

  // prep
  wswizB<<<192, 256, 0, stream>>>(qkv_w, qkvF, 256, 768);
  wswizB<<<64, 256, 0, stream>>>(proj_w, projF, 256, 256);
  wswiz1<<<256, 256, 0, stream>>>(fc1_w, W1f);
  wswiz2<<<256, 256, 0, stream>>>(fc2_w, W2f);
  bias_gb<<<512, 256, 0, stream>>>(rpb, rpi, biasb);

  for (int i = 0; i < 2; ++i) {
    int shift = i ? 8 : 0;
    const float* xin = i ? x_cur : x;

    ln_part<<<8192, 256, 0, stream>>>(xin, ln1_g + i * 256, ln1_b + i * 256, sbuf, shift);

    EpiParams ep{};
    ep.bias = qkv_b + i * 768; ep.obf = qkvb; ep.qscale = 0.17677669529663687f;
    gemm_fk2<<<dim3(3, 256), 512, 0, stream>>>(sbuf, qkvF + (size_t)i * 196608, 768, ep);

    attn_v3<<<1024, 256, 0, stream>>>(qkvb, biasb, i, sbuf);

    ep = EpiParams{};
    ep.bias = proj_b + i * 256; ep.of32 = x_cur; ep.resid = xin; ep.shift = shift;
    gemm_fk<2><<<dim3(2, 256), 512, 0, stream>>>(sbuf, projF + (size_t)i * 65536, 256, ep);

    fused_mlp<<<512, 512, 0, stream>>>(x_cur, ln2_g + i * 256, ln2_b + i * 256,
                                       W1f + (size_t)i * 262144, W2f + (size_t)i * 262144,
                                       fc1_b + i * 1024, fc2_b + i * 256,
                                       (i == 1) ? (float*)d_out : x_cur);
  }
}